// Round 5
// baseline (402.725 us; speedup 1.0000x reference)
//
#include <hip/hip_runtime.h>
#include <stdint.h>

#define N_NODES 100000
#define N_EDGES 1600000
#define IN_F 128
#define OUT_F 32

#define RB 128                    // rows per bucket (shift 7)
#define NB 782                    // ceil(N_NODES / RB)
#define ABLK 256                  // phase-A blocks
#define EPA (N_EDGES / ABLK)      // 6250 edges per phase-A block (exact)
#define NTOT (NB * ABLK)          // 200192 = 782 * 256
#define NBLK_SCAN (NTOT / 256)    // 782 (exact)
#define RCHUNK 2048               // records staged in LDS per chunk

// ---------------------------------------------------------------------------
// GEMM: support = x @ W   [N,128]x[128,32] -> [N,32]  (unchanged, known-good)
// ---------------------------------------------------------------------------
__global__ __launch_bounds__(256) void gcn_gemm2(const float* __restrict__ x,
                                                 const float* __restrict__ w,
                                                 float* __restrict__ support) {
    __shared__ float ws[IN_F][OUT_F];      // 16 KB
    __shared__ float xs[64][IN_F + 4];     // stride 132 floats
    const int tid = threadIdx.x;
    const int rowBase = blockIdx.x * 64;

    {
        float* wsf = &ws[0][0];
        #pragma unroll
        for (int chunk = 0; chunk < 4; ++chunk) {
            const int i = chunk * 1024 + tid * 4;
            *reinterpret_cast<float4*>(wsf + i) =
                *reinterpret_cast<const float4*>(&w[i]);
        }
    }
    #pragma unroll
    for (int chunk = 0; chunk < 8; ++chunk) {
        const int idx = chunk * 1024 + tid * 4;
        const int r = idx >> 7;
        const int c = idx & 127;
        if (rowBase + r < N_NODES) {
            *reinterpret_cast<float4*>(&xs[r][c]) =
                *reinterpret_cast<const float4*>(&x[(size_t)(rowBase + r) * IN_F + c]);
        }
    }
    __syncthreads();

    const int fg = tid & 7;
    const int rg = tid >> 3;
    const int f0 = fg * 4;
    const int r0 = rg * 2;

    float acc[2][4] = {{0.f, 0.f, 0.f, 0.f}, {0.f, 0.f, 0.f, 0.f}};
    for (int k0 = 0; k0 < IN_F; k0 += 4) {
        const float4 xa = *reinterpret_cast<const float4*>(&xs[r0][k0]);
        const float4 xb = *reinterpret_cast<const float4*>(&xs[r0 + 1][k0]);
        const float xav[4] = {xa.x, xa.y, xa.z, xa.w};
        const float xbv[4] = {xb.x, xb.y, xb.z, xb.w};
        #pragma unroll
        for (int j = 0; j < 4; ++j) {
            const float4 wv = *reinterpret_cast<const float4*>(&ws[k0 + j][f0]);
            acc[0][0] += xav[j] * wv.x;  acc[0][1] += xav[j] * wv.y;
            acc[0][2] += xav[j] * wv.z;  acc[0][3] += xav[j] * wv.w;
            acc[1][0] += xbv[j] * wv.x;  acc[1][1] += xbv[j] * wv.y;
            acc[1][2] += xbv[j] * wv.z;  acc[1][3] += xbv[j] * wv.w;
        }
    }
    #pragma unroll
    for (int i = 0; i < 2; ++i) {
        const int row = rowBase + r0 + i;
        if (row < N_NODES) {
            float4 v;
            v.x = acc[i][0]; v.y = acc[i][1]; v.z = acc[i][2]; v.w = acc[i][3];
            *reinterpret_cast<float4*>(&support[(size_t)row * OUT_F + f0]) = v;
        }
    }
}

// ---------------------------------------------------------------------------
// Phase A1: per-block bucket histogram. count[k*ABLK + b], k = row >> 7.
// ---------------------------------------------------------------------------
__global__ __launch_bounds__(256) void gcn_count(const int* __restrict__ row,
                                                 int* __restrict__ count) {
    __shared__ int h[NB];
    const int tid = threadIdx.x, b = blockIdx.x;
    for (int i = tid; i < NB; i += 256) h[i] = 0;
    __syncthreads();
    const int e0 = b * EPA;
    for (int i = tid; i < EPA; i += 256)
        atomicAdd(&h[row[e0 + i] >> 7], 1);
    __syncthreads();
    for (int i = tid; i < NB; i += 256)
        count[i * ABLK + b] = h[i];
}

// ---------------------------------------------------------------------------
// 3-phase exclusive scan over the flat NTOT count matrix.
// ---------------------------------------------------------------------------
__global__ __launch_bounds__(256) void scan_a(const int* __restrict__ count,
                                              int* __restrict__ ptr,
                                              int* __restrict__ bsum) {
    __shared__ int s[256];
    const int i = blockIdx.x * 256 + threadIdx.x;
    const int v = count[i];
    s[threadIdx.x] = v;
    __syncthreads();
    for (int off = 1; off < 256; off <<= 1) {
        const int t = (threadIdx.x >= off) ? s[threadIdx.x - off] : 0;
        __syncthreads();
        s[threadIdx.x] += t;
        __syncthreads();
    }
    ptr[i] = s[threadIdx.x] - v;
    if (threadIdx.x == 255) bsum[blockIdx.x] = s[255];
}

__global__ __launch_bounds__(1024) void scan_b(int* __restrict__ bsum) {
    __shared__ int s[1024];
    const int v = (threadIdx.x < NBLK_SCAN) ? bsum[threadIdx.x] : 0;
    s[threadIdx.x] = v;
    __syncthreads();
    for (int off = 1; off < 1024; off <<= 1) {
        const int t = (threadIdx.x >= off) ? s[threadIdx.x - off] : 0;
        __syncthreads();
        s[threadIdx.x] += t;
        __syncthreads();
    }
    if (threadIdx.x < NBLK_SCAN) bsum[threadIdx.x] = s[threadIdx.x] - v;  // exclusive
}

__global__ __launch_bounds__(256) void scan_c(int* __restrict__ ptr,
                                              const int* __restrict__ bsum) {
    const int i = blockIdx.x * 256 + threadIdx.x;
    ptr[i] += bsum[blockIdx.x];
}

// ---------------------------------------------------------------------------
// Phase A2: bin edges. (block,bucket) segments contiguous in rec[].
// Record: lo32 = col | (row_local << 17), hi32 = val bits.
// ---------------------------------------------------------------------------
__global__ __launch_bounds__(256) void gcn_bin(const int* __restrict__ row,
                                               const int* __restrict__ col,
                                               const float* __restrict__ val,
                                               const int* __restrict__ ptr,
                                               long long* __restrict__ rec) {
    __shared__ int cur[NB];
    const int tid = threadIdx.x, b = blockIdx.x;
    for (int i = tid; i < NB; i += 256) cur[i] = ptr[i * ABLK + b];
    __syncthreads();
    const int e0 = b * EPA;
    for (int i = tid; i < EPA; i += 256) {
        const int e = e0 + i;
        const int r = row[e];
        const int k = r >> 7;
        const int slot = atomicAdd(&cur[k], 1);
        const uint32_t lo = (uint32_t)col[e] | ((uint32_t)(r & 127) << 17);
        const uint64_t hi = (uint64_t)__float_as_uint(val[e]);
        rec[slot] = (long long)((hi << 32) | (uint64_t)lo);
    }
}

// ---------------------------------------------------------------------------
// Phase B v3: 1024 threads/block (32 edge-groups), one block per 128-row
// bucket. Records LDS-staged in 2048-rec chunks; batch-8 gathers pinned
// with sched_barrier(0); LDS fp32 tile; single float4 out write, bias fused.
// ---------------------------------------------------------------------------
__global__ __launch_bounds__(1024) void gcn_acc(const int* __restrict__ ptr,
                                                const long long* __restrict__ rec,
                                                const float* __restrict__ support,
                                                const float* __restrict__ bias,
                                                float* __restrict__ out) {
    __shared__ float acc[RB * OUT_F];       // 16 KB
    __shared__ long long rbuf[RCHUNK];      // 16 KB
    const int tid = threadIdx.x, k = blockIdx.x;

    {   // zero the tile: exactly one float4 per thread
        float4 z; z.x = 0.f; z.y = 0.f; z.z = 0.f; z.w = 0.f;
        *reinterpret_cast<float4*>(&acc[tid * 4]) = z;
    }
    __syncthreads();

    const int g = tid >> 5;          // edge-group 0..31
    const int f = tid & 31;          // feature lane
    const int start = ptr[k * ABLK];
    const int end = (k < NB - 1) ? ptr[(k + 1) * ABLK] : N_EDGES;

    for (int cb = start; cb < end; cb += RCHUNK) {
        const int n = min(RCHUNK, end - cb);
        // stage: coalesced, 2 recs per thread
        for (int i = tid; i < n; i += 1024) rbuf[i] = rec[cb + i];
        __syncthreads();

        const int nb = n >> 8;       // full 256-record super-batches
        for (int b = 0; b < nb; ++b) {
            const int base = b * 256 + g * 8;
            long long pk[8];
            #pragma unroll
            for (int j = 0; j < 8; ++j) pk[j] = rbuf[base + j];   // LDS broadcast
            float sv[8], vv[8];
            int rl[8];
            #pragma unroll
            for (int j = 0; j < 8; ++j) {
                const int c = (int)((uint64_t)pk[j] & 0x1ffff);
                rl[j] = (int)(((uint64_t)pk[j] >> 17) & 0x7f);
                vv[j] = __uint_as_float((uint32_t)((uint64_t)pk[j] >> 32));
                sv[j] = support[(size_t)c * OUT_F + f];          // 8 independent gathers
            }
            __builtin_amdgcn_sched_barrier(0);   // keep all 8 gathers issued before use
            #pragma unroll
            for (int j = 0; j < 8; ++j)
                atomicAdd(&acc[rl[j] * OUT_F + f], vv[j] * sv[j]);
        }
        // tail of chunk (< 256 records): stride-32 single-record path
        for (int i = (n & ~255) + g; i < n; i += 32) {
            const uint64_t pk = (uint64_t)rbuf[i];
            const int c  = (int)(pk & 0x1ffff);
            const int rl1 = (int)((pk >> 17) & 0x7f);
            const float v = __uint_as_float((uint32_t)(pk >> 32));
            atomicAdd(&acc[rl1 * OUT_F + f], v * support[(size_t)c * OUT_F + f]);
        }
        __syncthreads();
    }

    const int rowBase = k * RB;
    const int rb = min(RB, N_NODES - rowBase);
    const int n4 = (rb * OUT_F) / 4;
    if (tid < n4) {
        const float4 a = *reinterpret_cast<const float4*>(&acc[tid * 4]);
        const float4 bv = *reinterpret_cast<const float4*>(&bias[(tid * 4) & 31]);
        float4 o;
        o.x = a.x + bv.x; o.y = a.y + bv.y; o.z = a.z + bv.z; o.w = a.w + bv.w;
        *reinterpret_cast<float4*>(&out[(size_t)rowBase * OUT_F + tid * 4]) = o;
    }
}

// ---------------------------------------------------------------------------
// Fallback path (ws too small): round-1 atomic scatter
// ---------------------------------------------------------------------------
__global__ __launch_bounds__(256) void gcn_bias_init(const float* __restrict__ bias,
                                                     float* __restrict__ out) {
    const int i = blockIdx.x * 256 + threadIdx.x;
    if (i < N_NODES * OUT_F) out[i] = bias[i & 31];
}

__global__ __launch_bounds__(256) void gcn_scatter(const int* __restrict__ row,
                                                   const int* __restrict__ col,
                                                   const float* __restrict__ val,
                                                   const float* __restrict__ support,
                                                   float* __restrict__ out) {
    const int f = threadIdx.x & 31;
    const int grp = threadIdx.x >> 5;
    long long e = (long long)blockIdx.x * 8 + grp;
    const long long stride = (long long)gridDim.x * 8;
    for (; e < N_EDGES; e += stride) {
        const int r = row[e];
        const int c = col[e];
        const float v = val[e];
        const float s = support[(size_t)c * OUT_F + f];
        atomicAdd(&out[(size_t)r * OUT_F + f], v * s);
    }
}

extern "C" void kernel_launch(void* const* d_in, const int* in_sizes, int n_in,
                              void* d_out, int out_size, void* d_ws, size_t ws_size,
                              hipStream_t stream) {
    const float* x       = (const float*)d_in[0];
    const int*   adj_row = (const int*)d_in[1];
    const int*   adj_col = (const int*)d_in[2];
    const float* adj_val = (const float*)d_in[3];
    const float* weight  = (const float*)d_in[4];
    const float* bias    = (const float*)d_in[5];
    float* out = (float*)d_out;

    char* ws = (char*)d_ws;
    const size_t SUPPORT_B = (size_t)N_NODES * OUT_F * 4;     // 12,800,000
    const size_t REC_B     = (size_t)N_EDGES * 8;             // 12,800,000
    const size_t CNT_B     = ((size_t)NTOT * 4 + 255) & ~(size_t)255;
    const size_t BSUM_B    = ((size_t)NBLK_SCAN * 4 + 255) & ~(size_t)255;
    const size_t NEED = SUPPORT_B + REC_B + 2 * CNT_B + BSUM_B;

    float* support  = (float*)(ws);
    long long* rec  = (long long*)(ws + SUPPORT_B);
    int* count      = (int*)(ws + SUPPORT_B + REC_B);
    int* ptr        = (int*)(ws + SUPPORT_B + REC_B + CNT_B);
    int* bsum       = (int*)(ws + SUPPORT_B + REC_B + 2 * CNT_B);

    // 1) support = x @ W
    gcn_gemm2<<<(N_NODES + 63) / 64, 256, 0, stream>>>(x, weight, support);

    if (ws_size >= NEED) {
        // 2) blocked multisplit: count -> scan(3-phase) -> bin
        gcn_count<<<ABLK, 256, 0, stream>>>(adj_row, count);
        scan_a<<<NBLK_SCAN, 256, 0, stream>>>(count, ptr, bsum);
        scan_b<<<1, 1024, 0, stream>>>(bsum);
        scan_c<<<NBLK_SCAN, 256, 0, stream>>>(ptr, bsum);
        gcn_bin<<<ABLK, 256, 0, stream>>>(adj_row, adj_col, adj_val, ptr, rec);
        // 3) per-bucket staged+batched LDS accumulation, bias fused
        gcn_acc<<<NB, 1024, 0, stream>>>(ptr, rec, support, bias, out);
    } else {
        // Fallback: atomic scatter path
        gcn_bias_init<<<(N_NODES * OUT_F + 255) / 256, 256, 0, stream>>>(bias, out);
        gcn_scatter<<<8192, 256, 0, stream>>>(adj_row, adj_col, adj_val, support, out);
    }
}

// Round 6
// 172.103 us; speedup vs baseline: 2.3400x; 2.3400x over previous
//
#include <hip/hip_runtime.h>
#include <stdint.h>

#define N_NODES 100000
#define N_EDGES 1600000
#define IN_F 128
#define OUT_F 32

#define RB 64                     // rows per bucket (shift 6)
#define NB 1563                   // ceil(N_NODES / RB)
#define ABLK 256                  // phase-A blocks
#define EPA (N_EDGES / ABLK)      // 6250 edges per phase-A block (exact)
#define NTOT (NB * ABLK)          // 400128
#define NSA (NTOT / 256)          // 1563 scan_a blocks (exact)
#define CAP 1536                  // LDS record capacity per bucket (mean 1024, sigma 32)

// ---------------------------------------------------------------------------
// GEMM: support = x @ W   [N,128]x[128,32] -> [N,32]  (unchanged, known-good)
// ---------------------------------------------------------------------------
__global__ __launch_bounds__(256) void gcn_gemm2(const float* __restrict__ x,
                                                 const float* __restrict__ w,
                                                 float* __restrict__ support) {
    __shared__ float ws[IN_F][OUT_F];      // 16 KB
    __shared__ float xs[64][IN_F + 4];     // stride 132 floats
    const int tid = threadIdx.x;
    const int rowBase = blockIdx.x * 64;

    {
        float* wsf = &ws[0][0];
        #pragma unroll
        for (int chunk = 0; chunk < 4; ++chunk) {
            const int i = chunk * 1024 + tid * 4;
            *reinterpret_cast<float4*>(wsf + i) =
                *reinterpret_cast<const float4*>(&w[i]);
        }
    }
    #pragma unroll
    for (int chunk = 0; chunk < 8; ++chunk) {
        const int idx = chunk * 1024 + tid * 4;
        const int r = idx >> 7;
        const int c = idx & 127;
        if (rowBase + r < N_NODES) {
            *reinterpret_cast<float4*>(&xs[r][c]) =
                *reinterpret_cast<const float4*>(&x[(size_t)(rowBase + r) * IN_F + c]);
        }
    }
    __syncthreads();

    const int fg = tid & 7;
    const int rg = tid >> 3;
    const int f0 = fg * 4;
    const int r0 = rg * 2;

    float acc[2][4] = {{0.f, 0.f, 0.f, 0.f}, {0.f, 0.f, 0.f, 0.f}};
    for (int k0 = 0; k0 < IN_F; k0 += 4) {
        const float4 xa = *reinterpret_cast<const float4*>(&xs[r0][k0]);
        const float4 xb = *reinterpret_cast<const float4*>(&xs[r0 + 1][k0]);
        const float xav[4] = {xa.x, xa.y, xa.z, xa.w};
        const float xbv[4] = {xb.x, xb.y, xb.z, xb.w};
        #pragma unroll
        for (int j = 0; j < 4; ++j) {
            const float4 wv = *reinterpret_cast<const float4*>(&ws[k0 + j][f0]);
            acc[0][0] += xav[j] * wv.x;  acc[0][1] += xav[j] * wv.y;
            acc[0][2] += xav[j] * wv.z;  acc[0][3] += xav[j] * wv.w;
            acc[1][0] += xbv[j] * wv.x;  acc[1][1] += xbv[j] * wv.y;
            acc[1][2] += xbv[j] * wv.z;  acc[1][3] += xbv[j] * wv.w;
        }
    }
    #pragma unroll
    for (int i = 0; i < 2; ++i) {
        const int row = rowBase + r0 + i;
        if (row < N_NODES) {
            float4 v;
            v.x = acc[i][0]; v.y = acc[i][1]; v.z = acc[i][2]; v.w = acc[i][3];
            *reinterpret_cast<float4*>(&support[(size_t)row * OUT_F + f0]) = v;
        }
    }
}

// ---------------------------------------------------------------------------
// Phase A1: per-block bucket histogram. count[k*ABLK + b], k = row >> 6.
// ---------------------------------------------------------------------------
__global__ __launch_bounds__(256) void gcn_count(const int* __restrict__ row,
                                                 int* __restrict__ count) {
    __shared__ int h[NB];
    const int tid = threadIdx.x, b = blockIdx.x;
    for (int i = tid; i < NB; i += 256) h[i] = 0;
    __syncthreads();
    const int e0 = b * EPA;
    for (int i = tid; i < EPA; i += 256)
        atomicAdd(&h[row[e0 + i] >> 6], 1);
    __syncthreads();
    for (int i = tid; i < NB; i += 256)
        count[i * ABLK + b] = h[i];
}

// ---------------------------------------------------------------------------
// 3-phase exclusive scan over the flat NTOT count matrix.
// ---------------------------------------------------------------------------
__global__ __launch_bounds__(256) void scan_a(const int* __restrict__ count,
                                              int* __restrict__ ptr,
                                              int* __restrict__ bsum) {
    __shared__ int s[256];
    const int i = blockIdx.x * 256 + threadIdx.x;
    const int v = count[i];
    s[threadIdx.x] = v;
    __syncthreads();
    for (int off = 1; off < 256; off <<= 1) {
        const int t = (threadIdx.x >= off) ? s[threadIdx.x - off] : 0;
        __syncthreads();
        s[threadIdx.x] += t;
        __syncthreads();
    }
    ptr[i] = s[threadIdx.x] - v;
    if (threadIdx.x == 255) bsum[blockIdx.x] = s[255];
}

// scan_b: exclusive scan of NSA (1563) block sums; one block, 2 elems/thread.
__global__ __launch_bounds__(1024) void scan_b(int* __restrict__ bsum) {
    __shared__ int s[1024];
    const int t = threadIdx.x;
    const int v0 = (2 * t     < NSA) ? bsum[2 * t]     : 0;
    const int v1 = (2 * t + 1 < NSA) ? bsum[2 * t + 1] : 0;
    const int sum = v0 + v1;
    s[t] = sum;
    __syncthreads();
    for (int off = 1; off < 1024; off <<= 1) {
        const int x = (t >= off) ? s[t - off] : 0;
        __syncthreads();
        s[t] += x;
        __syncthreads();
    }
    const int excl = s[t] - sum;
    if (2 * t     < NSA) bsum[2 * t]     = excl;
    if (2 * t + 1 < NSA) bsum[2 * t + 1] = excl + v0;
}

__global__ __launch_bounds__(256) void scan_c(int* __restrict__ ptr,
                                              const int* __restrict__ bsum) {
    const int i = blockIdx.x * 256 + threadIdx.x;
    ptr[i] += bsum[blockIdx.x];
}

// ---------------------------------------------------------------------------
// Phase A2: bin edges. (block,bucket) segments contiguous in rec[].
// Record: lo32 = col | (row_local << 17), hi32 = val bits.  (col<2^17, rl<2^6)
// ---------------------------------------------------------------------------
__global__ __launch_bounds__(256) void gcn_bin(const int* __restrict__ row,
                                               const int* __restrict__ col,
                                               const float* __restrict__ val,
                                               const int* __restrict__ ptr,
                                               long long* __restrict__ rec) {
    __shared__ int cur[NB];
    const int tid = threadIdx.x, b = blockIdx.x;
    for (int i = tid; i < NB; i += 256) cur[i] = ptr[i * ABLK + b];
    __syncthreads();
    const int e0 = b * EPA;
    for (int i = tid; i < EPA; i += 256) {
        const int e = e0 + i;
        const int r = row[e];
        const int k = r >> 6;
        const int slot = atomicAdd(&cur[k], 1);
        const uint32_t lo = (uint32_t)col[e] | ((uint32_t)(r & 63) << 17);
        const uint64_t hi = (uint64_t)__float_as_uint(val[e]);
        rec[slot] = (long long)((hi << 32) | (uint64_t)lo);
    }
}

// ---------------------------------------------------------------------------
// Phase B v4: one block per 64-row bucket. Stage bucket recs in LDS, LDS
// counting-sort to exact row order, then REGISTER accumulation: 32 lanes per
// row iterate its edges (no atomics anywhere), single out write, bias fused.
// ---------------------------------------------------------------------------
__global__ __launch_bounds__(256) void gcn_rows(const int* __restrict__ ptr,
                                                const long long* __restrict__ rec,
                                                const float* __restrict__ support,
                                                const float* __restrict__ bias,
                                                float* __restrict__ out) {
    __shared__ long long rbuf[CAP];    // 12 KB
    __shared__ long long srt[CAP];     // 12 KB
    __shared__ int cnt[RB];            // reused as cursor after scan
    __shared__ int rs[RB + 1];         // row segment starts
    __shared__ float bs[OUT_F];
    const int tid = threadIdx.x, k = blockIdx.x;

    const int start = ptr[k * ABLK];
    const int end = (k < NB - 1) ? ptr[(k + 1) * ABLK] : N_EDGES;
    const int span = end - start;
    const int n = min(span, CAP);

    if (tid < OUT_F) bs[tid] = bias[tid];
    if (tid < RB) cnt[tid] = 0;
    // stage records (coalesced)
    for (int i = tid; i < n; i += 256) rbuf[i] = rec[start + i];
    __syncthreads();

    // histogram over 64 local rows
    for (int i = tid; i < n; i += 256)
        atomicAdd(&cnt[(int)(((uint64_t)rbuf[i] >> 17) & 63)], 1);
    __syncthreads();

    // exclusive scan of 64 counters in wave 0
    if (tid < 64) {
        const int v = cnt[tid];
        int sc = v;
        #pragma unroll
        for (int d = 1; d < 64; d <<= 1) {
            const int t2 = __shfl_up(sc, d, 64);
            if (tid >= d) sc += t2;
        }
        rs[tid] = sc - v;
        cnt[tid] = sc - v;     // cursor
        if (tid == 63) rs[64] = sc;
    }
    __syncthreads();

    // reorder into exact row order
    for (int i = tid; i < n; i += 256) {
        const long long pk = rbuf[i];
        const int rl = (int)(((uint64_t)pk >> 17) & 63);
        const int slot = atomicAdd(&cnt[rl], 1);
        srt[slot] = pk;
    }
    __syncthreads();

    // register accumulation: 4 waves x (2 rows per pass) x 8 passes = 64 rows
    const int wv = tid >> 6;          // wave 0..3
    const int lane = tid & 63;
    const int half = lane >> 5;       // row within pair
    const int f = lane & 31;          // feature
    const int rowBase = k * RB;

    for (int rp = 0; rp < 8; ++rp) {
        const int r = wv * 16 + rp * 2 + half;
        const int gr = rowBase + r;
        float a = bs[f];
        const int s0 = rs[r];
        const int s1 = rs[r + 1];
        for (int i = s0; i < s1; ++i) {
            const uint64_t pk = (uint64_t)srt[i];          // ds broadcast
            const int c = (int)(pk & 0x1ffff);
            const float v = __uint_as_float((uint32_t)(pk >> 32));
            a += v * support[(size_t)c * OUT_F + f];       // 128B coalesced gather
        }
        // overflow beyond LDS cap (statistically never; correctness guard)
        for (int i = CAP; i < span; ++i) {
            const uint64_t pk = (uint64_t)rec[start + i];
            if ((int)((pk >> 17) & 63) == r) {
                const int c = (int)(pk & 0x1ffff);
                const float v = __uint_as_float((uint32_t)(pk >> 32));
                a += v * support[(size_t)c * OUT_F + f];
            }
        }
        if (gr < N_NODES)
            out[(size_t)gr * OUT_F + f] = a;               // single plain store
    }
}

// ---------------------------------------------------------------------------
// Fallback path (ws too small): round-1 atomic scatter
// ---------------------------------------------------------------------------
__global__ __launch_bounds__(256) void gcn_bias_init(const float* __restrict__ bias,
                                                     float* __restrict__ out) {
    const int i = blockIdx.x * 256 + threadIdx.x;
    if (i < N_NODES * OUT_F) out[i] = bias[i & 31];
}

__global__ __launch_bounds__(256) void gcn_scatter(const int* __restrict__ row,
                                                   const int* __restrict__ col,
                                                   const float* __restrict__ val,
                                                   const float* __restrict__ support,
                                                   float* __restrict__ out) {
    const int f = threadIdx.x & 31;
    const int grp = threadIdx.x >> 5;
    long long e = (long long)blockIdx.x * 8 + grp;
    const long long stride = (long long)gridDim.x * 8;
    for (; e < N_EDGES; e += stride) {
        const int r = row[e];
        const int c = col[e];
        const float v = val[e];
        const float s = support[(size_t)c * OUT_F + f];
        atomicAdd(&out[(size_t)r * OUT_F + f], v * s);
    }
}

extern "C" void kernel_launch(void* const* d_in, const int* in_sizes, int n_in,
                              void* d_out, int out_size, void* d_ws, size_t ws_size,
                              hipStream_t stream) {
    const float* x       = (const float*)d_in[0];
    const int*   adj_row = (const int*)d_in[1];
    const int*   adj_col = (const int*)d_in[2];
    const float* adj_val = (const float*)d_in[3];
    const float* weight  = (const float*)d_in[4];
    const float* bias    = (const float*)d_in[5];
    float* out = (float*)d_out;

    char* ws = (char*)d_ws;
    const size_t SUPPORT_B = (size_t)N_NODES * OUT_F * 4;     // 12,800,000
    const size_t REC_B     = (size_t)N_EDGES * 8;             // 12,800,000
    const size_t CNT_B     = ((size_t)NTOT * 4 + 255) & ~(size_t)255;   // ~1.6 MB
    const size_t BSUM_B    = ((size_t)NSA * 4 + 255) & ~(size_t)255;
    const size_t NEED = SUPPORT_B + REC_B + 2 * CNT_B + BSUM_B;

    float* support  = (float*)(ws);
    long long* rec  = (long long*)(ws + SUPPORT_B);
    int* count      = (int*)(ws + SUPPORT_B + REC_B);
    int* ptr        = (int*)(ws + SUPPORT_B + REC_B + CNT_B);
    int* bsum       = (int*)(ws + SUPPORT_B + REC_B + 2 * CNT_B);

    // 1) support = x @ W
    gcn_gemm2<<<(N_NODES + 63) / 64, 256, 0, stream>>>(x, weight, support);

    if (ws_size >= NEED) {
        // 2) blocked multisplit: count -> scan(3-phase) -> bin
        gcn_count<<<ABLK, 256, 0, stream>>>(adj_row, count);
        scan_a<<<NSA, 256, 0, stream>>>(count, ptr, bsum);
        scan_b<<<1, 1024, 0, stream>>>(bsum);
        scan_c<<<NSA, 256, 0, stream>>>(ptr, bsum);
        gcn_bin<<<ABLK, 256, 0, stream>>>(adj_row, adj_col, adj_val, ptr, rec);
        // 3) per-bucket LDS counting-sort + register-accumulate gather
        gcn_rows<<<NB, 256, 0, stream>>>(ptr, rec, support, bias, out);
    } else {
        // Fallback: atomic scatter path
        gcn_bias_init<<<(N_NODES * OUT_F + 255) / 256, 256, 0, stream>>>(bias, out);
        gcn_scatter<<<8192, 256, 0, stream>>>(adj_row, adj_col, adj_val, support, out);
    }
}

// Round 7
// 101.499 us; speedup vs baseline: 3.9678x; 1.6956x over previous
//
#include <hip/hip_runtime.h>
#include <stdint.h>

#define N_NODES 100000
#define N_EDGES 1600000
#define IN_F 128
#define OUT_F 32

#define RB 64                     // rows per bucket (shift 6)
#define NB 1563                   // ceil(N_NODES / RB)
#define ABLK 256                  // phase-A blocks
#define EPA (N_EDGES / ABLK)      // 6250 edges per phase-A block (exact)
#define NTOT (NB * ABLK)          // 400128
#define NSA (NTOT / 256)          // 1563 scan_a blocks (exact)
#define CAP 1536                  // LDS record capacity per bucket (mean 1024, 16 sigma)

__device__ __forceinline__ float bf2f(unsigned short u) {
    return __uint_as_float(((uint32_t)u) << 16);
}
__device__ __forceinline__ unsigned short f2bf(float x) {
    const uint32_t b = __float_as_uint(x);
    return (unsigned short)((b + 0x7fffu + ((b >> 16) & 1u)) >> 16);   // RNE
}

// ---------------------------------------------------------------------------
// GEMM: support_bf16 = bf16(x @ W)   [N,128]x[128,32] -> [N,32] bf16
// ---------------------------------------------------------------------------
__global__ __launch_bounds__(256) void gcn_gemm2(const float* __restrict__ x,
                                                 const float* __restrict__ w,
                                                 unsigned short* __restrict__ support) {
    __shared__ float ws[IN_F][OUT_F];      // 16 KB
    __shared__ float xs[64][IN_F + 4];     // stride 132 floats (16B aligned)
    const int tid = threadIdx.x;
    const int rowBase = blockIdx.x * 64;

    {
        float* wsf = &ws[0][0];
        #pragma unroll
        for (int chunk = 0; chunk < 4; ++chunk) {
            const int i = chunk * 1024 + tid * 4;
            *reinterpret_cast<float4*>(wsf + i) =
                *reinterpret_cast<const float4*>(&w[i]);
        }
    }
    #pragma unroll
    for (int chunk = 0; chunk < 8; ++chunk) {
        const int idx = chunk * 1024 + tid * 4;
        const int r = idx >> 7;
        const int c = idx & 127;
        if (rowBase + r < N_NODES) {
            *reinterpret_cast<float4*>(&xs[r][c]) =
                *reinterpret_cast<const float4*>(&x[(size_t)(rowBase + r) * IN_F + c]);
        }
    }
    __syncthreads();

    const int fg = tid & 7;
    const int rg = tid >> 3;
    const int f0 = fg * 4;
    const int r0 = rg * 2;

    float acc[2][4] = {{0.f, 0.f, 0.f, 0.f}, {0.f, 0.f, 0.f, 0.f}};
    for (int k0 = 0; k0 < IN_F; k0 += 4) {
        const float4 xa = *reinterpret_cast<const float4*>(&xs[r0][k0]);
        const float4 xb = *reinterpret_cast<const float4*>(&xs[r0 + 1][k0]);
        const float xav[4] = {xa.x, xa.y, xa.z, xa.w};
        const float xbv[4] = {xb.x, xb.y, xb.z, xb.w};
        #pragma unroll
        for (int j = 0; j < 4; ++j) {
            const float4 wv = *reinterpret_cast<const float4*>(&ws[k0 + j][f0]);
            acc[0][0] += xav[j] * wv.x;  acc[0][1] += xav[j] * wv.y;
            acc[0][2] += xav[j] * wv.z;  acc[0][3] += xav[j] * wv.w;
            acc[1][0] += xbv[j] * wv.x;  acc[1][1] += xbv[j] * wv.y;
            acc[1][2] += xbv[j] * wv.z;  acc[1][3] += xbv[j] * wv.w;
        }
    }
    #pragma unroll
    for (int i = 0; i < 2; ++i) {
        const int row = rowBase + r0 + i;
        if (row < N_NODES) {
            ushort4 o;
            o.x = f2bf(acc[i][0]); o.y = f2bf(acc[i][1]);
            o.z = f2bf(acc[i][2]); o.w = f2bf(acc[i][3]);
            *reinterpret_cast<ushort4*>(&support[(size_t)row * OUT_F + f0]) = o;
        }
    }
}

// ---------------------------------------------------------------------------
// Phase A1: per-block bucket histogram. count[k*ABLK + b], k = row >> 6.
// ---------------------------------------------------------------------------
__global__ __launch_bounds__(256) void gcn_count(const int* __restrict__ row,
                                                 int* __restrict__ count) {
    __shared__ int h[NB];
    const int tid = threadIdx.x, b = blockIdx.x;
    for (int i = tid; i < NB; i += 256) h[i] = 0;
    __syncthreads();
    const int e0 = b * EPA;
    for (int i = tid; i < EPA; i += 256)
        atomicAdd(&h[row[e0 + i] >> 6], 1);
    __syncthreads();
    for (int i = tid; i < NB; i += 256)
        count[i * ABLK + b] = h[i];
}

// ---------------------------------------------------------------------------
// 3-phase exclusive scan over the flat NTOT count matrix.
// ---------------------------------------------------------------------------
__global__ __launch_bounds__(256) void scan_a(const int* __restrict__ count,
                                              int* __restrict__ ptr,
                                              int* __restrict__ bsum) {
    __shared__ int s[256];
    const int i = blockIdx.x * 256 + threadIdx.x;
    const int v = count[i];
    s[threadIdx.x] = v;
    __syncthreads();
    for (int off = 1; off < 256; off <<= 1) {
        const int t = (threadIdx.x >= off) ? s[threadIdx.x - off] : 0;
        __syncthreads();
        s[threadIdx.x] += t;
        __syncthreads();
    }
    ptr[i] = s[threadIdx.x] - v;
    if (threadIdx.x == 255) bsum[blockIdx.x] = s[255];
}

// scan_b: exclusive scan of NSA (1563) block sums; one block, 2 elems/thread.
__global__ __launch_bounds__(1024) void scan_b(int* __restrict__ bsum) {
    __shared__ int s[1024];
    const int t = threadIdx.x;
    const int v0 = (2 * t     < NSA) ? bsum[2 * t]     : 0;
    const int v1 = (2 * t + 1 < NSA) ? bsum[2 * t + 1] : 0;
    const int sum = v0 + v1;
    s[t] = sum;
    __syncthreads();
    for (int off = 1; off < 1024; off <<= 1) {
        const int x = (t >= off) ? s[t - off] : 0;
        __syncthreads();
        s[t] += x;
        __syncthreads();
    }
    const int excl = s[t] - sum;
    if (2 * t     < NSA) bsum[2 * t]     = excl;
    if (2 * t + 1 < NSA) bsum[2 * t + 1] = excl + v0;
}

__global__ __launch_bounds__(256) void scan_c(int* __restrict__ ptr,
                                              const int* __restrict__ bsum) {
    const int i = blockIdx.x * 256 + threadIdx.x;
    ptr[i] += bsum[blockIdx.x];
}

// ---------------------------------------------------------------------------
// Phase A2: bin edges. (block,bucket) segments contiguous in rec[].
// Record: lo32 = col | (row_local << 17), hi32 = val bits.  (col<2^17, rl<2^6)
// ---------------------------------------------------------------------------
__global__ __launch_bounds__(256) void gcn_bin(const int* __restrict__ row,
                                               const int* __restrict__ col,
                                               const float* __restrict__ val,
                                               const int* __restrict__ ptr,
                                               long long* __restrict__ rec) {
    __shared__ int cur[NB];
    const int tid = threadIdx.x, b = blockIdx.x;
    for (int i = tid; i < NB; i += 256) cur[i] = ptr[i * ABLK + b];
    __syncthreads();
    const int e0 = b * EPA;
    for (int i = tid; i < EPA; i += 256) {
        const int e = e0 + i;
        const int r = row[e];
        const int k = r >> 6;
        const int slot = atomicAdd(&cur[k], 1);
        const uint32_t lo = (uint32_t)col[e] | ((uint32_t)(r & 63) << 17);
        const uint64_t hi = (uint64_t)__float_as_uint(val[e]);
        rec[slot] = (long long)((hi << 32) | (uint64_t)lo);
    }
}

// ---------------------------------------------------------------------------
// Phase B v5: 512 threads (16 row-groups), one block per 64-row bucket.
// LDS counting-sort to exact row order, then register accumulation with a
// 4-deep unrolled gather pipeline (named scalars, 4 accumulators, no atomics).
// ---------------------------------------------------------------------------
__global__ __launch_bounds__(512) void gcn_rows(const int* __restrict__ ptr,
                                                const long long* __restrict__ rec,
                                                const unsigned short* __restrict__ sup,
                                                const float* __restrict__ bias,
                                                float* __restrict__ out) {
    __shared__ long long rbuf[CAP];    // 12 KB
    __shared__ long long srt[CAP];     // 12 KB
    __shared__ int cnt[RB];            // reused as cursor after scan
    __shared__ int rs[RB + 1];         // row segment starts
    __shared__ float bs[OUT_F];
    const int tid = threadIdx.x, k = blockIdx.x;

    const int start = ptr[k * ABLK];
    const int end = (k < NB - 1) ? ptr[(k + 1) * ABLK] : N_EDGES;
    const int span = end - start;
    const int n = min(span, CAP);

    if (tid < OUT_F) bs[tid] = bias[tid];
    if (tid < RB) cnt[tid] = 0;
    for (int i = tid; i < n; i += 512) rbuf[i] = rec[start + i];   // coalesced stage
    __syncthreads();

    for (int i = tid; i < n; i += 512)
        atomicAdd(&cnt[(int)(((uint64_t)rbuf[i] >> 17) & 63)], 1);
    __syncthreads();

    if (tid < 64) {      // exclusive scan of 64 counters in wave 0
        const int v = cnt[tid];
        int sc = v;
        #pragma unroll
        for (int d = 1; d < 64; d <<= 1) {
            const int t2 = __shfl_up(sc, d, 64);
            if (tid >= d) sc += t2;
        }
        rs[tid] = sc - v;
        cnt[tid] = sc - v;
        if (tid == 63) rs[64] = sc;
    }
    __syncthreads();

    for (int i = tid; i < n; i += 512) {        // reorder into exact row order
        const long long pk = rbuf[i];
        const int rl = (int)(((uint64_t)pk >> 17) & 63);
        const int slot = atomicAdd(&cnt[rl], 1);
        srt[slot] = pk;
    }
    __syncthreads();

    // register accumulation: 16 groups x 4 passes = 64 rows
    const int g = tid >> 5;           // row-group 0..15
    const int f = tid & 31;           // feature
    const int rowBase = k * RB;

    for (int rp = 0; rp < 4; ++rp) {
        const int r = rp * 16 + g;
        const int gr = rowBase + r;
        const int s0 = rs[r];
        const int s1 = rs[r + 1];
        float a0 = bs[f], a1 = 0.f, a2 = 0.f, a3 = 0.f;
        int i = s0;
        for (; i + 4 <= s1; i += 4) {
            const uint64_t p0 = (uint64_t)srt[i];
            const uint64_t p1 = (uint64_t)srt[i + 1];
            const uint64_t p2 = (uint64_t)srt[i + 2];
            const uint64_t p3 = (uint64_t)srt[i + 3];
            const unsigned short q0 = sup[(size_t)(p0 & 0x1ffff) * OUT_F + f];
            const unsigned short q1 = sup[(size_t)(p1 & 0x1ffff) * OUT_F + f];
            const unsigned short q2 = sup[(size_t)(p2 & 0x1ffff) * OUT_F + f];
            const unsigned short q3 = sup[(size_t)(p3 & 0x1ffff) * OUT_F + f];
            a0 += __uint_as_float((uint32_t)(p0 >> 32)) * bf2f(q0);
            a1 += __uint_as_float((uint32_t)(p1 >> 32)) * bf2f(q1);
            a2 += __uint_as_float((uint32_t)(p2 >> 32)) * bf2f(q2);
            a3 += __uint_as_float((uint32_t)(p3 >> 32)) * bf2f(q3);
        }
        for (; i < s1; ++i) {
            const uint64_t pk = (uint64_t)srt[i];
            const unsigned short q = sup[(size_t)(pk & 0x1ffff) * OUT_F + f];
            a0 += __uint_as_float((uint32_t)(pk >> 32)) * bf2f(q);
        }
        // overflow beyond LDS cap (16 sigma; correctness guard only)
        for (int j = CAP; j < span; ++j) {
            const uint64_t pk = (uint64_t)rec[start + j];
            if ((int)((pk >> 17) & 63) == r) {
                const unsigned short q = sup[(size_t)(pk & 0x1ffff) * OUT_F + f];
                a0 += __uint_as_float((uint32_t)(pk >> 32)) * bf2f(q);
            }
        }
        if (gr < N_NODES)
            out[(size_t)gr * OUT_F + f] = (a0 + a1) + (a2 + a3);
    }
}

// ---------------------------------------------------------------------------
// Fallback path (ws too small): atomic scatter (bf16 support)
// ---------------------------------------------------------------------------
__global__ __launch_bounds__(256) void gcn_bias_init(const float* __restrict__ bias,
                                                     float* __restrict__ out) {
    const int i = blockIdx.x * 256 + threadIdx.x;
    if (i < N_NODES * OUT_F) out[i] = bias[i & 31];
}

__global__ __launch_bounds__(256) void gcn_scatter(const int* __restrict__ row,
                                                   const int* __restrict__ col,
                                                   const float* __restrict__ val,
                                                   const unsigned short* __restrict__ sup,
                                                   float* __restrict__ out) {
    const int f = threadIdx.x & 31;
    const int grp = threadIdx.x >> 5;
    long long e = (long long)blockIdx.x * 8 + grp;
    const long long stride = (long long)gridDim.x * 8;
    for (; e < N_EDGES; e += stride) {
        const int r = row[e];
        const int c = col[e];
        const float v = val[e];
        const float s = bf2f(sup[(size_t)c * OUT_F + f]);
        atomicAdd(&out[(size_t)r * OUT_F + f], v * s);
    }
}

extern "C" void kernel_launch(void* const* d_in, const int* in_sizes, int n_in,
                              void* d_out, int out_size, void* d_ws, size_t ws_size,
                              hipStream_t stream) {
    const float* x       = (const float*)d_in[0];
    const int*   adj_row = (const int*)d_in[1];
    const int*   adj_col = (const int*)d_in[2];
    const float* adj_val = (const float*)d_in[3];
    const float* weight  = (const float*)d_in[4];
    const float* bias    = (const float*)d_in[5];
    float* out = (float*)d_out;

    char* ws = (char*)d_ws;
    const size_t SUPPORT_B = (((size_t)N_NODES * OUT_F * 2) + 255) & ~(size_t)255;  // 6.4 MB bf16
    const size_t REC_B     = (size_t)N_EDGES * 8;                                   // 12.8 MB
    const size_t CNT_B     = ((size_t)NTOT * 4 + 255) & ~(size_t)255;               // ~1.6 MB
    const size_t BSUM_B    = ((size_t)NSA * 4 + 255) & ~(size_t)255;
    const size_t NEED = SUPPORT_B + REC_B + 2 * CNT_B + BSUM_B;

    unsigned short* support = (unsigned short*)(ws);
    long long* rec  = (long long*)(ws + SUPPORT_B);
    int* count      = (int*)(ws + SUPPORT_B + REC_B);
    int* ptr        = (int*)(ws + SUPPORT_B + REC_B + CNT_B);
    int* bsum       = (int*)(ws + SUPPORT_B + REC_B + 2 * CNT_B);

    // 1) support = bf16(x @ W)
    gcn_gemm2<<<(N_NODES + 63) / 64, 256, 0, stream>>>(x, weight, support);

    if (ws_size >= NEED) {
        // 2) blocked multisplit: count -> scan(3-phase) -> bin
        gcn_count<<<ABLK, 256, 0, stream>>>(adj_row, count);
        scan_a<<<NSA, 256, 0, stream>>>(count, ptr, bsum);
        scan_b<<<1, 1024, 0, stream>>>(bsum);
        scan_c<<<NSA, 256, 0, stream>>>(ptr, bsum);
        gcn_bin<<<ABLK, 256, 0, stream>>>(adj_row, adj_col, adj_val, ptr, rec);
        // 3) per-bucket counting-sort + 4-deep pipelined register gather
        gcn_rows<<<NB, 512, 0, stream>>>(ptr, rec, support, bias, out);
    } else {
        gcn_bias_init<<<(N_NODES * OUT_F + 255) / 256, 256, 0, stream>>>(bias, out);
        gcn_scatter<<<8192, 256, 0, stream>>>(adj_row, adj_col, adj_val, support, out);
    }
}

// Round 8
// 91.395 us; speedup vs baseline: 4.4064x; 1.1106x over previous
//
#include <hip/hip_runtime.h>
#include <stdint.h>

#define N_NODES 100000
#define N_EDGES 1600000
#define IN_F 128
#define OUT_F 32

#define RB 64                     // rows per bucket (shift 6)
#define NB 1563                   // ceil(N_NODES / RB)
#define ABLK 256                  // phase-A blocks; MUST be 256 (scan alignment)
#define EPA (N_EDGES / ABLK)      // 6250 edges per phase-A block (exact)
#define NTOT (NB * ABLK)          // 400128
#define NSA NB                    // scan_a blocks == buckets (ABLK==256 identity)
#define CAP 1536                  // LDS record capacity per bucket (mean 1024, 16 sigma)

__device__ __forceinline__ float bf2f(unsigned short u) {
    return __uint_as_float(((uint32_t)u) << 16);
}
__device__ __forceinline__ unsigned short f2bf(float x) {
    const uint32_t b = __float_as_uint(x);
    return (unsigned short)((b + 0x7fffu + ((b >> 16) & 1u)) >> 16);   // RNE
}

// ---------------------------------------------------------------------------
// GEMM: support_bf16 = bf16(x @ W)   [N,128]x[128,32] -> [N,32] bf16
// ---------------------------------------------------------------------------
__global__ __launch_bounds__(256) void gcn_gemm2(const float* __restrict__ x,
                                                 const float* __restrict__ w,
                                                 unsigned short* __restrict__ support) {
    __shared__ float ws[IN_F][OUT_F];      // 16 KB
    __shared__ float xs[64][IN_F + 4];     // stride 132 floats (16B aligned)
    const int tid = threadIdx.x;
    const int rowBase = blockIdx.x * 64;

    {
        float* wsf = &ws[0][0];
        #pragma unroll
        for (int chunk = 0; chunk < 4; ++chunk) {
            const int i = chunk * 1024 + tid * 4;
            *reinterpret_cast<float4*>(wsf + i) =
                *reinterpret_cast<const float4*>(&w[i]);
        }
    }
    #pragma unroll
    for (int chunk = 0; chunk < 8; ++chunk) {
        const int idx = chunk * 1024 + tid * 4;
        const int r = idx >> 7;
        const int c = idx & 127;
        if (rowBase + r < N_NODES) {
            *reinterpret_cast<float4*>(&xs[r][c]) =
                *reinterpret_cast<const float4*>(&x[(size_t)(rowBase + r) * IN_F + c]);
        }
    }
    __syncthreads();

    const int fg = tid & 7;
    const int rg = tid >> 3;
    const int f0 = fg * 4;
    const int r0 = rg * 2;

    float acc[2][4] = {{0.f, 0.f, 0.f, 0.f}, {0.f, 0.f, 0.f, 0.f}};
    for (int k0 = 0; k0 < IN_F; k0 += 4) {
        const float4 xa = *reinterpret_cast<const float4*>(&xs[r0][k0]);
        const float4 xb = *reinterpret_cast<const float4*>(&xs[r0 + 1][k0]);
        const float xav[4] = {xa.x, xa.y, xa.z, xa.w};
        const float xbv[4] = {xb.x, xb.y, xb.z, xb.w};
        #pragma unroll
        for (int j = 0; j < 4; ++j) {
            const float4 wv = *reinterpret_cast<const float4*>(&ws[k0 + j][f0]);
            acc[0][0] += xav[j] * wv.x;  acc[0][1] += xav[j] * wv.y;
            acc[0][2] += xav[j] * wv.z;  acc[0][3] += xav[j] * wv.w;
            acc[1][0] += xbv[j] * wv.x;  acc[1][1] += xbv[j] * wv.y;
            acc[1][2] += xbv[j] * wv.z;  acc[1][3] += xbv[j] * wv.w;
        }
    }
    #pragma unroll
    for (int i = 0; i < 2; ++i) {
        const int row = rowBase + r0 + i;
        if (row < N_NODES) {
            ushort4 o;
            o.x = f2bf(acc[i][0]); o.y = f2bf(acc[i][1]);
            o.z = f2bf(acc[i][2]); o.w = f2bf(acc[i][3]);
            *reinterpret_cast<ushort4*>(&support[(size_t)row * OUT_F + f0]) = o;
        }
    }
}

// ---------------------------------------------------------------------------
// Phase A1: per-block bucket histogram (1024 thr). count[k*ABLK+b], k=row>>6.
// ---------------------------------------------------------------------------
__global__ __launch_bounds__(1024) void gcn_count(const int* __restrict__ row,
                                                  int* __restrict__ count) {
    __shared__ int h[NB];
    const int tid = threadIdx.x, b = blockIdx.x;
    for (int i = tid; i < NB; i += 1024) h[i] = 0;
    __syncthreads();
    const int e0 = b * EPA;
    for (int i = tid; i < EPA; i += 1024)
        atomicAdd(&h[row[e0 + i] >> 6], 1);
    __syncthreads();
    for (int i = tid; i < NB; i += 1024)
        count[i * ABLK + b] = h[i];
}

// ---------------------------------------------------------------------------
// scan_a: block-local exclusive scan (one 256-elem scan-block per bucket).
// ptr[k*256] == 0 always; bucket k's global start lives in bsum[k] after scan_b.
// ---------------------------------------------------------------------------
__global__ __launch_bounds__(256) void scan_a(const int* __restrict__ count,
                                              int* __restrict__ ptr,
                                              int* __restrict__ bsum) {
    __shared__ int s[256];
    const int i = blockIdx.x * 256 + threadIdx.x;
    const int v = count[i];
    s[threadIdx.x] = v;
    __syncthreads();
    for (int off = 1; off < 256; off <<= 1) {
        const int t = (threadIdx.x >= off) ? s[threadIdx.x - off] : 0;
        __syncthreads();
        s[threadIdx.x] += t;
        __syncthreads();
    }
    ptr[i] = s[threadIdx.x] - v;
    if (threadIdx.x == 255) bsum[blockIdx.x] = s[255];
}

// scan_b: exclusive scan of NSA (1563) bucket sums; one block, 2 elems/thread.
__global__ __launch_bounds__(1024) void scan_b(int* __restrict__ bsum) {
    __shared__ int s[1024];
    const int t = threadIdx.x;
    const int v0 = (2 * t     < NSA) ? bsum[2 * t]     : 0;
    const int v1 = (2 * t + 1 < NSA) ? bsum[2 * t + 1] : 0;
    const int sum = v0 + v1;
    s[t] = sum;
    __syncthreads();
    for (int off = 1; off < 1024; off <<= 1) {
        const int x = (t >= off) ? s[t - off] : 0;
        __syncthreads();
        s[t] += x;
        __syncthreads();
    }
    const int excl = s[t] - sum;
    if (2 * t     < NSA) bsum[2 * t]     = excl;
    if (2 * t + 1 < NSA) bsum[2 * t + 1] = excl + v0;
}

// ---------------------------------------------------------------------------
// Phase A2: bin edges (1024 thr). cur[i] = bsum[i] + ptr[i*256 + b].
// Record: lo32 = col | (row_local << 17), hi32 = val bits.
// ---------------------------------------------------------------------------
__global__ __launch_bounds__(1024) void gcn_bin(const int* __restrict__ row,
                                                const int* __restrict__ col,
                                                const float* __restrict__ val,
                                                const int* __restrict__ ptr,
                                                const int* __restrict__ bsum,
                                                long long* __restrict__ rec) {
    __shared__ int cur[NB];
    const int tid = threadIdx.x, b = blockIdx.x;
    for (int i = tid; i < NB; i += 1024)
        cur[i] = bsum[i] + ptr[i * ABLK + b];
    __syncthreads();
    const int e0 = b * EPA;
    for (int i = tid; i < EPA; i += 1024) {
        const int e = e0 + i;
        const int r = row[e];
        const int k = r >> 6;
        const int slot = atomicAdd(&cur[k], 1);
        const uint32_t lo = (uint32_t)col[e] | ((uint32_t)(r & 63) << 17);
        const uint64_t hi = (uint64_t)__float_as_uint(val[e]);
        rec[slot] = (long long)((hi << 32) | (uint64_t)lo);
    }
}

// ---------------------------------------------------------------------------
// Phase B: 512 threads (16 row-groups), one block per 64-row bucket.
// LDS counting-sort to exact row order, then register accumulation with a
// 4-deep unrolled gather pipeline. Bucket bounds come straight from bsum.
// ---------------------------------------------------------------------------
__global__ __launch_bounds__(512) void gcn_rows(const int* __restrict__ bsum,
                                                const long long* __restrict__ rec,
                                                const unsigned short* __restrict__ sup,
                                                const float* __restrict__ bias,
                                                float* __restrict__ out) {
    __shared__ long long rbuf[CAP];    // 12 KB
    __shared__ long long srt[CAP];     // 12 KB
    __shared__ int cnt[RB];            // reused as cursor after scan
    __shared__ int rs[RB + 1];         // row segment starts
    __shared__ float bs[OUT_F];
    const int tid = threadIdx.x, k = blockIdx.x;

    const int start = bsum[k];
    const int end = (k < NB - 1) ? bsum[k + 1] : N_EDGES;
    const int span = end - start;
    const int n = min(span, CAP);

    if (tid < OUT_F) bs[tid] = bias[tid];
    if (tid < RB) cnt[tid] = 0;
    for (int i = tid; i < n; i += 512) rbuf[i] = rec[start + i];   // coalesced stage
    __syncthreads();

    for (int i = tid; i < n; i += 512)
        atomicAdd(&cnt[(int)(((uint64_t)rbuf[i] >> 17) & 63)], 1);
    __syncthreads();

    if (tid < 64) {      // exclusive scan of 64 counters in wave 0
        const int v = cnt[tid];
        int sc = v;
        #pragma unroll
        for (int d = 1; d < 64; d <<= 1) {
            const int t2 = __shfl_up(sc, d, 64);
            if (tid >= d) sc += t2;
        }
        rs[tid] = sc - v;
        cnt[tid] = sc - v;
        if (tid == 63) rs[64] = sc;
    }
    __syncthreads();

    for (int i = tid; i < n; i += 512) {        // reorder into exact row order
        const long long pk = rbuf[i];
        const int rl = (int)(((uint64_t)pk >> 17) & 63);
        const int slot = atomicAdd(&cnt[rl], 1);
        srt[slot] = pk;
    }
    __syncthreads();

    // register accumulation: 16 groups x 4 passes = 64 rows
    const int g = tid >> 5;           // row-group 0..15
    const int f = tid & 31;           // feature
    const int rowBase = k * RB;

    for (int rp = 0; rp < 4; ++rp) {
        const int r = rp * 16 + g;
        const int gr = rowBase + r;
        const int s0 = rs[r];
        const int s1 = rs[r + 1];
        float a0 = bs[f], a1 = 0.f, a2 = 0.f, a3 = 0.f;
        int i = s0;
        for (; i + 4 <= s1; i += 4) {
            const uint64_t p0 = (uint64_t)srt[i];
            const uint64_t p1 = (uint64_t)srt[i + 1];
            const uint64_t p2 = (uint64_t)srt[i + 2];
            const uint64_t p3 = (uint64_t)srt[i + 3];
            const unsigned short q0 = sup[(size_t)(p0 & 0x1ffff) * OUT_F + f];
            const unsigned short q1 = sup[(size_t)(p1 & 0x1ffff) * OUT_F + f];
            const unsigned short q2 = sup[(size_t)(p2 & 0x1ffff) * OUT_F + f];
            const unsigned short q3 = sup[(size_t)(p3 & 0x1ffff) * OUT_F + f];
            a0 += __uint_as_float((uint32_t)(p0 >> 32)) * bf2f(q0);
            a1 += __uint_as_float((uint32_t)(p1 >> 32)) * bf2f(q1);
            a2 += __uint_as_float((uint32_t)(p2 >> 32)) * bf2f(q2);
            a3 += __uint_as_float((uint32_t)(p3 >> 32)) * bf2f(q3);
        }
        for (; i < s1; ++i) {
            const uint64_t pk = (uint64_t)srt[i];
            const unsigned short q = sup[(size_t)(pk & 0x1ffff) * OUT_F + f];
            a0 += __uint_as_float((uint32_t)(pk >> 32)) * bf2f(q);
        }
        // overflow beyond LDS cap (16 sigma; correctness guard only)
        for (int j = CAP; j < span; ++j) {
            const uint64_t pk = (uint64_t)rec[start + j];
            if ((int)((pk >> 17) & 63) == r) {
                const unsigned short q = sup[(size_t)(pk & 0x1ffff) * OUT_F + f];
                a0 += __uint_as_float((uint32_t)(pk >> 32)) * bf2f(q);
            }
        }
        if (gr < N_NODES)
            out[(size_t)gr * OUT_F + f] = (a0 + a1) + (a2 + a3);
    }
}

// ---------------------------------------------------------------------------
// Fallback path (ws too small): atomic scatter (bf16 support)
// ---------------------------------------------------------------------------
__global__ __launch_bounds__(256) void gcn_bias_init(const float* __restrict__ bias,
                                                     float* __restrict__ out) {
    const int i = blockIdx.x * 256 + threadIdx.x;
    if (i < N_NODES * OUT_F) out[i] = bias[i & 31];
}

__global__ __launch_bounds__(256) void gcn_scatter(const int* __restrict__ row,
                                                   const int* __restrict__ col,
                                                   const float* __restrict__ val,
                                                   const unsigned short* __restrict__ sup,
                                                   float* __restrict__ out) {
    const int f = threadIdx.x & 31;
    const int grp = threadIdx.x >> 5;
    long long e = (long long)blockIdx.x * 8 + grp;
    const long long stride = (long long)gridDim.x * 8;
    for (; e < N_EDGES; e += stride) {
        const int r = row[e];
        const int c = col[e];
        const float v = val[e];
        const float s = bf2f(sup[(size_t)c * OUT_F + f]);
        atomicAdd(&out[(size_t)r * OUT_F + f], v * s);
    }
}

extern "C" void kernel_launch(void* const* d_in, const int* in_sizes, int n_in,
                              void* d_out, int out_size, void* d_ws, size_t ws_size,
                              hipStream_t stream) {
    const float* x       = (const float*)d_in[0];
    const int*   adj_row = (const int*)d_in[1];
    const int*   adj_col = (const int*)d_in[2];
    const float* adj_val = (const float*)d_in[3];
    const float* weight  = (const float*)d_in[4];
    const float* bias    = (const float*)d_in[5];
    float* out = (float*)d_out;

    char* ws = (char*)d_ws;
    const size_t SUPPORT_B = (((size_t)N_NODES * OUT_F * 2) + 255) & ~(size_t)255;  // 6.4 MB bf16
    const size_t REC_B     = (size_t)N_EDGES * 8;                                   // 12.8 MB
    const size_t CNT_B     = ((size_t)NTOT * 4 + 255) & ~(size_t)255;               // ~1.6 MB
    const size_t BSUM_B    = ((size_t)NSA * 4 + 255) & ~(size_t)255;
    const size_t NEED = SUPPORT_B + REC_B + 2 * CNT_B + BSUM_B;

    unsigned short* support = (unsigned short*)(ws);
    long long* rec  = (long long*)(ws + SUPPORT_B);
    int* count      = (int*)(ws + SUPPORT_B + REC_B);
    int* ptr        = (int*)(ws + SUPPORT_B + REC_B + CNT_B);
    int* bsum       = (int*)(ws + SUPPORT_B + REC_B + 2 * CNT_B);

    // 1) support = bf16(x @ W)
    gcn_gemm2<<<(N_NODES + 63) / 64, 256, 0, stream>>>(x, weight, support);

    if (ws_size >= NEED) {
        // 2) blocked multisplit: count -> scan_a -> scan_b -> bin
        gcn_count<<<ABLK, 1024, 0, stream>>>(adj_row, count);
        scan_a<<<NSA, 256, 0, stream>>>(count, ptr, bsum);
        scan_b<<<1, 1024, 0, stream>>>(bsum);
        gcn_bin<<<ABLK, 1024, 0, stream>>>(adj_row, adj_col, adj_val, ptr, bsum, rec);
        // 3) per-bucket counting-sort + 4-deep pipelined register gather
        gcn_rows<<<NB, 512, 0, stream>>>(bsum, rec, support, bias, out);
    } else {
        gcn_bias_init<<<(N_NODES * OUT_F + 255) / 256, 256, 0, stream>>>(bias, out);
        gcn_scatter<<<8192, 256, 0, stream>>>(adj_row, adj_col, adj_val, support, out);
    }
}

// Round 9
// 84.981 us; speedup vs baseline: 4.7390x; 1.0755x over previous
//
#include <hip/hip_runtime.h>
#include <stdint.h>

#define N_NODES 100000
#define N_EDGES 1600000
#define IN_F 128
#define OUT_F 32

#define RB 64                     // rows per bucket (shift 6)
#define NB 1563                   // ceil(N_NODES / RB)
#define ABLK 256                  // phase-A blocks; MUST be 256 (scan alignment)
#define EPA (N_EDGES / ABLK)      // 6250 edges per phase-A block (exact)
#define NTOT (NB * ABLK)          // 400128
#define NSA NB                    // scan_a blocks == buckets (ABLK==256 identity)
#define CAP 1536                  // LDS record capacity per bucket (mean 1024, 16 sigma)
#define MTILES (N_NODES / 16)     // 6250 row-tiles for MFMA gemm (exact)

typedef __attribute__((ext_vector_type(8))) short bf16x8;
typedef __attribute__((ext_vector_type(4))) float f32x4;

__device__ __forceinline__ float bf2f(unsigned short u) {
    return __uint_as_float(((uint32_t)u) << 16);
}
__device__ __forceinline__ unsigned short f2bf(float x) {
    const uint32_t b = __float_as_uint(x);
    return (unsigned short)((b + 0x7fffu + ((b >> 16) & 1u)) >> 16);   // RNE
}

// ---------------------------------------------------------------------------
// GEMM v3 (MFMA): support_bf16 = bf16(x @ W)  via v_mfma_f32_16x16x32_bf16.
// Per wave: one 16-row tile, 2 N-tiles x 4 K-steps = 8 MFMAs.
// A read direct from global (16 rows x 128B contiguous per k-step);
// W transposed->bf16 in LDS once per block; B-frags hoisted to registers.
// ---------------------------------------------------------------------------
__global__ __launch_bounds__(256) void gcn_gemm3(const float* __restrict__ x,
                                                 const float* __restrict__ w,
                                                 unsigned short* __restrict__ support) {
    __shared__ unsigned short wt[OUT_F][IN_F + 8];   // [f][k], stride 136 (2-way free)
    const int tid = threadIdx.x;

    // stage W transposed + bf16: 4096 elems, coalesced fp32 reads
    #pragma unroll
    for (int i = tid; i < IN_F * OUT_F; i += 256) {
        const int k = i >> 5, f = i & 31;
        wt[f][k] = f2bf(w[i]);
    }
    __syncthreads();

    const int wv = tid >> 6;                 // wave 0..3
    const int lane = tid & 63;
    const int rowT = blockIdx.x * 4 + wv;    // 16-row tile index
    if (rowT >= MTILES) return;              // no syncs after this point
    const int row0 = rowT * 16;

    const int mrow = lane & 15;              // A row / C col index
    const int kg = lane >> 4;                // k-group 0..3
    const int kb = kg * 8;                   // k offset within 32-block

    // B fragments (wave-invariant): [kstep][ntile]
    bf16x8 bfrag[4][2];
    #pragma unroll
    for (int ks = 0; ks < 4; ++ks) {
        #pragma unroll
        for (int nt = 0; nt < 2; ++nt) {
            bfrag[ks][nt] = *reinterpret_cast<const bf16x8*>(
                &wt[mrow + nt * 16][ks * 32 + kb]);     // 16B aligned (136*2=272=16*17)
        }
    }

    f32x4 acc0 = {0.f, 0.f, 0.f, 0.f};
    f32x4 acc1 = {0.f, 0.f, 0.f, 0.f};
    const float* xr = &x[(size_t)(row0 + mrow) * IN_F];
    #pragma unroll
    for (int ks = 0; ks < 4; ++ks) {
        const float4 a0 = *reinterpret_cast<const float4*>(&xr[ks * 32 + kb]);
        const float4 a1 = *reinterpret_cast<const float4*>(&xr[ks * 32 + kb + 4]);
        bf16x8 af;
        af[0] = (short)f2bf(a0.x); af[1] = (short)f2bf(a0.y);
        af[2] = (short)f2bf(a0.z); af[3] = (short)f2bf(a0.w);
        af[4] = (short)f2bf(a1.x); af[5] = (short)f2bf(a1.y);
        af[6] = (short)f2bf(a1.z); af[7] = (short)f2bf(a1.w);
        acc0 = __builtin_amdgcn_mfma_f32_16x16x32_bf16(af, bfrag[ks][0], acc0, 0, 0, 0);
        acc1 = __builtin_amdgcn_mfma_f32_16x16x32_bf16(af, bfrag[ks][1], acc1, 0, 0, 0);
    }

    // C/D layout: col = lane&15, row = (lane>>4)*4 + reg   [m89/m91 verified]
    #pragma unroll
    for (int r = 0; r < 4; ++r) {
        const int orow = row0 + kg * 4 + r;
        support[(size_t)orow * OUT_F + mrow]      = f2bf(acc0[r]);
        support[(size_t)orow * OUT_F + mrow + 16] = f2bf(acc1[r]);
    }
}

// ---------------------------------------------------------------------------
// Phase A1: per-block bucket histogram (1024 thr). count[k*ABLK+b], k=row>>6.
// ---------------------------------------------------------------------------
__global__ __launch_bounds__(1024) void gcn_count(const int* __restrict__ row,
                                                  int* __restrict__ count) {
    __shared__ int h[NB];
    const int tid = threadIdx.x, b = blockIdx.x;
    for (int i = tid; i < NB; i += 1024) h[i] = 0;
    __syncthreads();
    const int e0 = b * EPA;
    for (int i = tid; i < EPA; i += 1024)
        atomicAdd(&h[row[e0 + i] >> 6], 1);
    __syncthreads();
    for (int i = tid; i < NB; i += 1024)
        count[i * ABLK + b] = h[i];
}

// ---------------------------------------------------------------------------
// scan_a: block-local exclusive scan (one 256-elem scan-block per bucket).
// ptr[k*256] == 0 always; bucket k's global start lives in bsum[k] after scan_b.
// ---------------------------------------------------------------------------
__global__ __launch_bounds__(256) void scan_a(const int* __restrict__ count,
                                              int* __restrict__ ptr,
                                              int* __restrict__ bsum) {
    __shared__ int s[256];
    const int i = blockIdx.x * 256 + threadIdx.x;
    const int v = count[i];
    s[threadIdx.x] = v;
    __syncthreads();
    for (int off = 1; off < 256; off <<= 1) {
        const int t = (threadIdx.x >= off) ? s[threadIdx.x - off] : 0;
        __syncthreads();
        s[threadIdx.x] += t;
        __syncthreads();
    }
    ptr[i] = s[threadIdx.x] - v;
    if (threadIdx.x == 255) bsum[blockIdx.x] = s[255];
}

// scan_b: exclusive scan of NSA (1563) bucket sums; one block, 2 elems/thread.
__global__ __launch_bounds__(1024) void scan_b(int* __restrict__ bsum) {
    __shared__ int s[1024];
    const int t = threadIdx.x;
    const int v0 = (2 * t     < NSA) ? bsum[2 * t]     : 0;
    const int v1 = (2 * t + 1 < NSA) ? bsum[2 * t + 1] : 0;
    const int sum = v0 + v1;
    s[t] = sum;
    __syncthreads();
    for (int off = 1; off < 1024; off <<= 1) {
        const int x = (t >= off) ? s[t - off] : 0;
        __syncthreads();
        s[t] += x;
        __syncthreads();
    }
    const int excl = s[t] - sum;
    if (2 * t     < NSA) bsum[2 * t]     = excl;
    if (2 * t + 1 < NSA) bsum[2 * t + 1] = excl + v0;
}

// ---------------------------------------------------------------------------
// Phase A2: bin edges (1024 thr). cur[i] = bsum[i] + ptr[i*256 + b].
// Record: lo32 = col | (row_local << 17), hi32 = val bits.
// ---------------------------------------------------------------------------
__global__ __launch_bounds__(1024) void gcn_bin(const int* __restrict__ row,
                                                const int* __restrict__ col,
                                                const float* __restrict__ val,
                                                const int* __restrict__ ptr,
                                                const int* __restrict__ bsum,
                                                long long* __restrict__ rec) {
    __shared__ int cur[NB];
    const int tid = threadIdx.x, b = blockIdx.x;
    for (int i = tid; i < NB; i += 1024)
        cur[i] = bsum[i] + ptr[i * ABLK + b];
    __syncthreads();
    const int e0 = b * EPA;
    for (int i = tid; i < EPA; i += 1024) {
        const int e = e0 + i;
        const int r = row[e];
        const int k = r >> 6;
        const int slot = atomicAdd(&cur[k], 1);
        const uint32_t lo = (uint32_t)col[e] | ((uint32_t)(r & 63) << 17);
        const uint64_t hi = (uint64_t)__float_as_uint(val[e]);
        rec[slot] = (long long)((hi << 32) | (uint64_t)lo);
    }
}

// ---------------------------------------------------------------------------
// Phase B: 512 threads (16 row-groups), one block per 64-row bucket.
// LDS counting-sort to exact row order, then register accumulation with a
// 4-deep unrolled gather pipeline. Bucket bounds come straight from bsum.
// ---------------------------------------------------------------------------
__global__ __launch_bounds__(512) void gcn_rows(const int* __restrict__ bsum,
                                                const long long* __restrict__ rec,
                                                const unsigned short* __restrict__ sup,
                                                const float* __restrict__ bias,
                                                float* __restrict__ out) {
    __shared__ long long rbuf[CAP];    // 12 KB
    __shared__ long long srt[CAP];     // 12 KB
    __shared__ int cnt[RB];            // reused as cursor after scan
    __shared__ int rs[RB + 1];         // row segment starts
    __shared__ float bs[OUT_F];
    const int tid = threadIdx.x, k = blockIdx.x;

    const int start = bsum[k];
    const int end = (k < NB - 1) ? bsum[k + 1] : N_EDGES;
    const int span = end - start;
    const int n = min(span, CAP);

    if (tid < OUT_F) bs[tid] = bias[tid];
    if (tid < RB) cnt[tid] = 0;
    for (int i = tid; i < n; i += 512) rbuf[i] = rec[start + i];   // coalesced stage
    __syncthreads();

    for (int i = tid; i < n; i += 512)
        atomicAdd(&cnt[(int)(((uint64_t)rbuf[i] >> 17) & 63)], 1);
    __syncthreads();

    if (tid < 64) {      // exclusive scan of 64 counters in wave 0
        const int v = cnt[tid];
        int sc = v;
        #pragma unroll
        for (int d = 1; d < 64; d <<= 1) {
            const int t2 = __shfl_up(sc, d, 64);
            if (tid >= d) sc += t2;
        }
        rs[tid] = sc - v;
        cnt[tid] = sc - v;
        if (tid == 63) rs[64] = sc;
    }
    __syncthreads();

    for (int i = tid; i < n; i += 512) {        // reorder into exact row order
        const long long pk = rbuf[i];
        const int rl = (int)(((uint64_t)pk >> 17) & 63);
        const int slot = atomicAdd(&cnt[rl], 1);
        srt[slot] = pk;
    }
    __syncthreads();

    // register accumulation: 16 groups x 4 passes = 64 rows
    const int g = tid >> 5;           // row-group 0..15
    const int f = tid & 31;           // feature
    const int rowBase = k * RB;

    for (int rp = 0; rp < 4; ++rp) {
        const int r = rp * 16 + g;
        const int gr = rowBase + r;
        const int s0 = rs[r];
        const int s1 = rs[r + 1];
        float a0 = bs[f], a1 = 0.f, a2 = 0.f, a3 = 0.f;
        int i = s0;
        for (; i + 4 <= s1; i += 4) {
            const uint64_t p0 = (uint64_t)srt[i];
            const uint64_t p1 = (uint64_t)srt[i + 1];
            const uint64_t p2 = (uint64_t)srt[i + 2];
            const uint64_t p3 = (uint64_t)srt[i + 3];
            const unsigned short q0 = sup[(size_t)(p0 & 0x1ffff) * OUT_F + f];
            const unsigned short q1 = sup[(size_t)(p1 & 0x1ffff) * OUT_F + f];
            const unsigned short q2 = sup[(size_t)(p2 & 0x1ffff) * OUT_F + f];
            const unsigned short q3 = sup[(size_t)(p3 & 0x1ffff) * OUT_F + f];
            a0 += __uint_as_float((uint32_t)(p0 >> 32)) * bf2f(q0);
            a1 += __uint_as_float((uint32_t)(p1 >> 32)) * bf2f(q1);
            a2 += __uint_as_float((uint32_t)(p2 >> 32)) * bf2f(q2);
            a3 += __uint_as_float((uint32_t)(p3 >> 32)) * bf2f(q3);
        }
        for (; i < s1; ++i) {
            const uint64_t pk = (uint64_t)srt[i];
            const unsigned short q = sup[(size_t)(pk & 0x1ffff) * OUT_F + f];
            a0 += __uint_as_float((uint32_t)(pk >> 32)) * bf2f(q);
        }
        // overflow beyond LDS cap (16 sigma; correctness guard only)
        for (int j = CAP; j < span; ++j) {
            const uint64_t pk = (uint64_t)rec[start + j];
            if ((int)((pk >> 17) & 63) == r) {
                const unsigned short q = sup[(size_t)(pk & 0x1ffff) * OUT_F + f];
                a0 += __uint_as_float((uint32_t)(pk >> 32)) * bf2f(q);
            }
        }
        if (gr < N_NODES)
            out[(size_t)gr * OUT_F + f] = (a0 + a1) + (a2 + a3);
    }
}

// ---------------------------------------------------------------------------
// Fallback path (ws too small): atomic scatter (bf16 support)
// ---------------------------------------------------------------------------
__global__ __launch_bounds__(256) void gcn_bias_init(const float* __restrict__ bias,
                                                     float* __restrict__ out) {
    const int i = blockIdx.x * 256 + threadIdx.x;
    if (i < N_NODES * OUT_F) out[i] = bias[i & 31];
}

__global__ __launch_bounds__(256) void gcn_scatter(const int* __restrict__ row,
                                                   const int* __restrict__ col,
                                                   const float* __restrict__ val,
                                                   const unsigned short* __restrict__ sup,
                                                   float* __restrict__ out) {
    const int f = threadIdx.x & 31;
    const int grp = threadIdx.x >> 5;
    long long e = (long long)blockIdx.x * 8 + grp;
    const long long stride = (long long)gridDim.x * 8;
    for (; e < N_EDGES; e += stride) {
        const int r = row[e];
        const int c = col[e];
        const float v = val[e];
        const float s = bf2f(sup[(size_t)c * OUT_F + f]);
        atomicAdd(&out[(size_t)r * OUT_F + f], v * s);
    }
}

extern "C" void kernel_launch(void* const* d_in, const int* in_sizes, int n_in,
                              void* d_out, int out_size, void* d_ws, size_t ws_size,
                              hipStream_t stream) {
    const float* x       = (const float*)d_in[0];
    const int*   adj_row = (const int*)d_in[1];
    const int*   adj_col = (const int*)d_in[2];
    const float* adj_val = (const float*)d_in[3];
    const float* weight  = (const float*)d_in[4];
    const float* bias    = (const float*)d_in[5];
    float* out = (float*)d_out;

    char* ws = (char*)d_ws;
    const size_t SUPPORT_B = (((size_t)N_NODES * OUT_F * 2) + 255) & ~(size_t)255;  // 6.4 MB bf16
    const size_t REC_B     = (size_t)N_EDGES * 8;                                   // 12.8 MB
    const size_t CNT_B     = ((size_t)NTOT * 4 + 255) & ~(size_t)255;               // ~1.6 MB
    const size_t BSUM_B    = ((size_t)NSA * 4 + 255) & ~(size_t)255;
    const size_t NEED = SUPPORT_B + REC_B + 2 * CNT_B + BSUM_B;

    unsigned short* support = (unsigned short*)(ws);
    long long* rec  = (long long*)(ws + SUPPORT_B);
    int* count      = (int*)(ws + SUPPORT_B + REC_B);
    int* ptr        = (int*)(ws + SUPPORT_B + REC_B + CNT_B);
    int* bsum       = (int*)(ws + SUPPORT_B + REC_B + 2 * CNT_B);

    // 1) support = bf16(x @ W) via MFMA
    gcn_gemm3<<<(MTILES + 3) / 4, 256, 0, stream>>>(x, weight, support);

    if (ws_size >= NEED) {
        // 2) blocked multisplit: count -> scan_a -> scan_b -> bin
        gcn_count<<<ABLK, 1024, 0, stream>>>(adj_row, count);
        scan_a<<<NSA, 256, 0, stream>>>(count, ptr, bsum);
        scan_b<<<1, 1024, 0, stream>>>(bsum);
        gcn_bin<<<ABLK, 1024, 0, stream>>>(adj_row, adj_col, adj_val, ptr, bsum, rec);
        // 3) per-bucket counting-sort + 4-deep pipelined register gather
        gcn_rows<<<NB, 512, 0, stream>>>(bsum, rec, support, bias, out);
    } else {
        gcn_bias_init<<<(N_NODES * OUT_F + 255) / 256, 256, 0, stream>>>(bias, out);
        gcn_scatter<<<8192, 256, 0, stream>>>(adj_row, adj_col, adj_val, support, out);
    }
}

// Round 10
// 83.586 us; speedup vs baseline: 4.8181x; 1.0167x over previous
//
#include <hip/hip_runtime.h>
#include <stdint.h>

#define N_NODES 100000
#define N_EDGES 1600000
#define IN_F 128
#define OUT_F 32

#define RB 64                     // rows per bucket (shift 6)
#define NB 1563                   // ceil(N_NODES / RB)
#define ABLK 256                  // phase-A blocks; MUST be 256 (scan alignment)
#define EPA (N_EDGES / ABLK)      // 6250 edges per phase-A block (exact)
#define NTOT (NB * ABLK)          // 400128
#define NSA NB                    // scan_a blocks == buckets (ABLK==256 identity)
#define CAP 1536                  // LDS record capacity per bucket (mean 1024, 16 sigma)
#define MTILES (N_NODES / 16)     // 6250 row-tiles for MFMA gemm (exact)
#define GEMM_BLKS ((MTILES + 7) / 8)   // 782 gemm blocks (8 waves x 1 tile)

typedef __attribute__((ext_vector_type(8))) short bf16x8;
typedef __attribute__((ext_vector_type(4))) float f32x4;

__device__ __forceinline__ float bf2f(unsigned short u) {
    return __uint_as_float(((uint32_t)u) << 16);
}
__device__ __forceinline__ unsigned short f2bf(float x) {
    const uint32_t b = __float_as_uint(x);
    return (unsigned short)((b + 0x7fffu + ((b >> 16) & 1u)) >> 16);   // RNE
}

// ---------------------------------------------------------------------------
// K1 (fused): blocks [0,GEMM_BLKS) do MFMA GEMM; blocks [GEMM_BLKS, +ABLK)
// do the bucket histogram. Independent work, one launch.
// ---------------------------------------------------------------------------
__global__ __launch_bounds__(512) void gcn_gemm_count(const float* __restrict__ x,
                                                      const float* __restrict__ w,
                                                      unsigned short* __restrict__ support,
                                                      const int* __restrict__ row,
                                                      int* __restrict__ count) {
    __shared__ unsigned short wt[OUT_F][IN_F + 8];   // gemm part: 8.7 KB
    __shared__ int h[NB];                            // count part: 6.25 KB
    const int tid = threadIdx.x;

    if (blockIdx.x < GEMM_BLKS) {
        // ---------------- GEMM: support = bf16(x @ W) ----------------
        #pragma unroll
        for (int i = tid; i < IN_F * OUT_F; i += 512) {
            const int k = i >> 5, f = i & 31;
            wt[f][k] = f2bf(w[i]);
        }
        __syncthreads();

        const int wv = tid >> 6;                 // wave 0..7
        const int lane = tid & 63;
        const int rowT = blockIdx.x * 8 + wv;    // 16-row tile index
        if (rowT >= MTILES) return;
        const int row0 = rowT * 16;

        const int mrow = lane & 15;              // A row / C col index
        const int kg = lane >> 4;                // k-group 0..3
        const int kb = kg * 8;

        bf16x8 bfrag[4][2];
        #pragma unroll
        for (int ks = 0; ks < 4; ++ks) {
            #pragma unroll
            for (int nt = 0; nt < 2; ++nt) {
                bfrag[ks][nt] = *reinterpret_cast<const bf16x8*>(
                    &wt[mrow + nt * 16][ks * 32 + kb]);
            }
        }

        f32x4 acc0 = {0.f, 0.f, 0.f, 0.f};
        f32x4 acc1 = {0.f, 0.f, 0.f, 0.f};
        const float* xr = &x[(size_t)(row0 + mrow) * IN_F];
        #pragma unroll
        for (int ks = 0; ks < 4; ++ks) {
            const float4 a0 = *reinterpret_cast<const float4*>(&xr[ks * 32 + kb]);
            const float4 a1 = *reinterpret_cast<const float4*>(&xr[ks * 32 + kb + 4]);
            bf16x8 af;
            af[0] = (short)f2bf(a0.x); af[1] = (short)f2bf(a0.y);
            af[2] = (short)f2bf(a0.z); af[3] = (short)f2bf(a0.w);
            af[4] = (short)f2bf(a1.x); af[5] = (short)f2bf(a1.y);
            af[6] = (short)f2bf(a1.z); af[7] = (short)f2bf(a1.w);
            acc0 = __builtin_amdgcn_mfma_f32_16x16x32_bf16(af, bfrag[ks][0], acc0, 0, 0, 0);
            acc1 = __builtin_amdgcn_mfma_f32_16x16x32_bf16(af, bfrag[ks][1], acc1, 0, 0, 0);
        }
        #pragma unroll
        for (int r = 0; r < 4; ++r) {
            const int orow = row0 + kg * 4 + r;
            support[(size_t)orow * OUT_F + mrow]      = f2bf(acc0[r]);
            support[(size_t)orow * OUT_F + mrow + 16] = f2bf(acc1[r]);
        }
    } else {
        // ---------------- COUNT: per-block bucket histogram ----------------
        const int b = blockIdx.x - GEMM_BLKS;
        for (int i = tid; i < NB; i += 512) h[i] = 0;
        __syncthreads();
        const int e0 = b * EPA;
        for (int i = tid; i < EPA; i += 512)
            atomicAdd(&h[row[e0 + i] >> 6], 1);
        __syncthreads();
        for (int i = tid; i < NB; i += 512)
            count[i * ABLK + b] = h[i];
    }
}

// ---------------------------------------------------------------------------
// scan_a: block-local exclusive scan (one 256-elem scan-block per bucket).
// ptr[k*256] == 0 always; bucket k's global start lives in bsum[k] after scan_b.
// ---------------------------------------------------------------------------
__global__ __launch_bounds__(256) void scan_a(const int* __restrict__ count,
                                              int* __restrict__ ptr,
                                              int* __restrict__ bsum) {
    __shared__ int s[256];
    const int i = blockIdx.x * 256 + threadIdx.x;
    const int v = count[i];
    s[threadIdx.x] = v;
    __syncthreads();
    for (int off = 1; off < 256; off <<= 1) {
        const int t = (threadIdx.x >= off) ? s[threadIdx.x - off] : 0;
        __syncthreads();
        s[threadIdx.x] += t;
        __syncthreads();
    }
    ptr[i] = s[threadIdx.x] - v;
    if (threadIdx.x == 255) bsum[blockIdx.x] = s[255];
}

// scan_b: exclusive scan of NSA (1563) bucket sums; one block, 2 elems/thread.
__global__ __launch_bounds__(1024) void scan_b(int* __restrict__ bsum) {
    __shared__ int s[1024];
    const int t = threadIdx.x;
    const int v0 = (2 * t     < NSA) ? bsum[2 * t]     : 0;
    const int v1 = (2 * t + 1 < NSA) ? bsum[2 * t + 1] : 0;
    const int sum = v0 + v1;
    s[t] = sum;
    __syncthreads();
    for (int off = 1; off < 1024; off <<= 1) {
        const int x = (t >= off) ? s[t - off] : 0;
        __syncthreads();
        s[t] += x;
        __syncthreads();
    }
    const int excl = s[t] - sum;
    if (2 * t     < NSA) bsum[2 * t]     = excl;
    if (2 * t + 1 < NSA) bsum[2 * t + 1] = excl + v0;
}

// ---------------------------------------------------------------------------
// Phase A2: bin edges (1024 thr, 4-batch MLP). cur[i] = bsum[i] + ptr[i*256+b].
// Record: lo32 = col | (row_local << 17), hi32 = val bits.
// ---------------------------------------------------------------------------
__global__ __launch_bounds__(1024) void gcn_bin(const int* __restrict__ row,
                                                const int* __restrict__ col,
                                                const float* __restrict__ val,
                                                const int* __restrict__ ptr,
                                                const int* __restrict__ bsum,
                                                long long* __restrict__ rec) {
    __shared__ int cur[NB];
    const int tid = threadIdx.x, b = blockIdx.x;
    for (int i = tid; i < NB; i += 1024)
        cur[i] = bsum[i] + ptr[i * ABLK + b];
    __syncthreads();
    const int e0 = b * EPA;

    int i = tid;
    for (; i + 3 * 1024 < EPA; i += 4 * 1024) {
        // 12 independent loads
        const int r0 = row[e0 + i];
        const int r1 = row[e0 + i + 1024];
        const int r2 = row[e0 + i + 2048];
        const int r3 = row[e0 + i + 3072];
        const int c0 = col[e0 + i];
        const int c1 = col[e0 + i + 1024];
        const int c2 = col[e0 + i + 2048];
        const int c3 = col[e0 + i + 3072];
        const uint32_t v0 = __float_as_uint(val[e0 + i]);
        const uint32_t v1 = __float_as_uint(val[e0 + i + 1024]);
        const uint32_t v2 = __float_as_uint(val[e0 + i + 2048]);
        const uint32_t v3 = __float_as_uint(val[e0 + i + 3072]);
        // 4 LDS atomics
        const int s0 = atomicAdd(&cur[r0 >> 6], 1);
        const int s1 = atomicAdd(&cur[r1 >> 6], 1);
        const int s2 = atomicAdd(&cur[r2 >> 6], 1);
        const int s3 = atomicAdd(&cur[r3 >> 6], 1);
        // 4 stores
        rec[s0] = (long long)(((uint64_t)v0 << 32) |
                  (uint64_t)((uint32_t)c0 | ((uint32_t)(r0 & 63) << 17)));
        rec[s1] = (long long)(((uint64_t)v1 << 32) |
                  (uint64_t)((uint32_t)c1 | ((uint32_t)(r1 & 63) << 17)));
        rec[s2] = (long long)(((uint64_t)v2 << 32) |
                  (uint64_t)((uint32_t)c2 | ((uint32_t)(r2 & 63) << 17)));
        rec[s3] = (long long)(((uint64_t)v3 << 32) |
                  (uint64_t)((uint32_t)c3 | ((uint32_t)(r3 & 63) << 17)));
    }
    for (; i < EPA; i += 1024) {
        const int e = e0 + i;
        const int r = row[e];
        const int slot = atomicAdd(&cur[r >> 6], 1);
        rec[slot] = (long long)(((uint64_t)__float_as_uint(val[e]) << 32) |
                    (uint64_t)((uint32_t)col[e] | ((uint32_t)(r & 63) << 17)));
    }
}

// ---------------------------------------------------------------------------
// Phase B: 1024 threads (32 row-groups x 2 passes), one block per bucket.
// LDS counting-sort to exact row order, then register accumulation with a
// 4-deep unrolled gather pipeline. Bucket bounds come straight from bsum.
// ---------------------------------------------------------------------------
__global__ __launch_bounds__(1024) void gcn_rows(const int* __restrict__ bsum,
                                                 const long long* __restrict__ rec,
                                                 const unsigned short* __restrict__ sup,
                                                 const float* __restrict__ bias,
                                                 float* __restrict__ out) {
    __shared__ long long rbuf[CAP];    // 12 KB
    __shared__ long long srt[CAP];     // 12 KB
    __shared__ int cnt[RB];            // reused as cursor after scan
    __shared__ int rs[RB + 1];         // row segment starts
    __shared__ float bs[OUT_F];
    const int tid = threadIdx.x, k = blockIdx.x;

    const int start = bsum[k];
    const int end = (k < NB - 1) ? bsum[k + 1] : N_EDGES;
    const int span = end - start;
    const int n = min(span, CAP);

    if (tid < OUT_F) bs[tid] = bias[tid];
    if (tid < RB) cnt[tid] = 0;
    for (int i = tid; i < n; i += 1024) rbuf[i] = rec[start + i];   // coalesced stage
    __syncthreads();

    for (int i = tid; i < n; i += 1024)
        atomicAdd(&cnt[(int)(((uint64_t)rbuf[i] >> 17) & 63)], 1);
    __syncthreads();

    if (tid < 64) {      // exclusive scan of 64 counters in wave 0
        const int v = cnt[tid];
        int sc = v;
        #pragma unroll
        for (int d = 1; d < 64; d <<= 1) {
            const int t2 = __shfl_up(sc, d, 64);
            if (tid >= d) sc += t2;
        }
        rs[tid] = sc - v;
        cnt[tid] = sc - v;
        if (tid == 63) rs[64] = sc;
    }
    __syncthreads();

    for (int i = tid; i < n; i += 1024) {       // reorder into exact row order
        const long long pk = rbuf[i];
        const int rl = (int)(((uint64_t)pk >> 17) & 63);
        const int slot = atomicAdd(&cnt[rl], 1);
        srt[slot] = pk;
    }
    __syncthreads();

    // register accumulation: 32 groups x 2 passes = 64 rows
    const int g = tid >> 5;           // row-group 0..31
    const int f = tid & 31;           // feature
    const int rowBase = k * RB;

    for (int rp = 0; rp < 2; ++rp) {
        const int r = rp * 32 + g;
        const int gr = rowBase + r;
        const int s0 = rs[r];
        const int s1 = rs[r + 1];
        float a0 = bs[f], a1 = 0.f, a2 = 0.f, a3 = 0.f;
        int i = s0;
        for (; i + 4 <= s1; i += 4) {
            const uint64_t p0 = (uint64_t)srt[i];
            const uint64_t p1 = (uint64_t)srt[i + 1];
            const uint64_t p2 = (uint64_t)srt[i + 2];
            const uint64_t p3 = (uint64_t)srt[i + 3];
            const unsigned short q0 = sup[(size_t)(p0 & 0x1ffff) * OUT_F + f];
            const unsigned short q1 = sup[(size_t)(p1 & 0x1ffff) * OUT_F + f];
            const unsigned short q2 = sup[(size_t)(p2 & 0x1ffff) * OUT_F + f];
            const unsigned short q3 = sup[(size_t)(p3 & 0x1ffff) * OUT_F + f];
            a0 += __uint_as_float((uint32_t)(p0 >> 32)) * bf2f(q0);
            a1 += __uint_as_float((uint32_t)(p1 >> 32)) * bf2f(q1);
            a2 += __uint_as_float((uint32_t)(p2 >> 32)) * bf2f(q2);
            a3 += __uint_as_float((uint32_t)(p3 >> 32)) * bf2f(q3);
        }
        for (; i < s1; ++i) {
            const uint64_t pk = (uint64_t)srt[i];
            const unsigned short q = sup[(size_t)(pk & 0x1ffff) * OUT_F + f];
            a0 += __uint_as_float((uint32_t)(pk >> 32)) * bf2f(q);
        }
        // overflow beyond LDS cap (16 sigma; correctness guard only)
        for (int j = CAP; j < span; ++j) {
            const uint64_t pk = (uint64_t)rec[start + j];
            if ((int)((pk >> 17) & 63) == r) {
                const unsigned short q = sup[(size_t)(pk & 0x1ffff) * OUT_F + f];
                a0 += __uint_as_float((uint32_t)(pk >> 32)) * bf2f(q);
            }
        }
        if (gr < N_NODES)
            out[(size_t)gr * OUT_F + f] = (a0 + a1) + (a2 + a3);
    }
}

// ---------------------------------------------------------------------------
// Fallback path (ws too small): atomic scatter (needs support in fp32-less ws)
// ---------------------------------------------------------------------------
__global__ __launch_bounds__(256) void gcn_bias_init(const float* __restrict__ bias,
                                                     float* __restrict__ out) {
    const int i = blockIdx.x * 256 + threadIdx.x;
    if (i < N_NODES * OUT_F) out[i] = bias[i & 31];
}

__global__ __launch_bounds__(256) void gcn_scatter(const int* __restrict__ row,
                                                   const int* __restrict__ col,
                                                   const float* __restrict__ val,
                                                   const unsigned short* __restrict__ sup,
                                                   float* __restrict__ out) {
    const int f = threadIdx.x & 31;
    const int grp = threadIdx.x >> 5;
    long long e = (long long)blockIdx.x * 8 + grp;
    const long long stride = (long long)gridDim.x * 8;
    for (; e < N_EDGES; e += stride) {
        const int r = row[e];
        const int c = col[e];
        const float v = val[e];
        const float s = bf2f(sup[(size_t)c * OUT_F + f]);
        atomicAdd(&out[(size_t)r * OUT_F + f], v * s);
    }
}

extern "C" void kernel_launch(void* const* d_in, const int* in_sizes, int n_in,
                              void* d_out, int out_size, void* d_ws, size_t ws_size,
                              hipStream_t stream) {
    const float* x       = (const float*)d_in[0];
    const int*   adj_row = (const int*)d_in[1];
    const int*   adj_col = (const int*)d_in[2];
    const float* adj_val = (const float*)d_in[3];
    const float* weight  = (const float*)d_in[4];
    const float* bias    = (const float*)d_in[5];
    float* out = (float*)d_out;

    char* ws = (char*)d_ws;
    const size_t SUPPORT_B = (((size_t)N_NODES * OUT_F * 2) + 255) & ~(size_t)255;  // 6.4 MB bf16
    const size_t REC_B     = (size_t)N_EDGES * 8;                                   // 12.8 MB
    const size_t CNT_B     = ((size_t)NTOT * 4 + 255) & ~(size_t)255;               // ~1.6 MB
    const size_t BSUM_B    = ((size_t)NSA * 4 + 255) & ~(size_t)255;
    const size_t NEED = SUPPORT_B + REC_B + 2 * CNT_B + BSUM_B;

    unsigned short* support = (unsigned short*)(ws);
    long long* rec  = (long long*)(ws + SUPPORT_B);
    int* count      = (int*)(ws + SUPPORT_B + REC_B);
    int* ptr        = (int*)(ws + SUPPORT_B + REC_B + CNT_B);
    int* bsum       = (int*)(ws + SUPPORT_B + REC_B + 2 * CNT_B);

    if (ws_size >= NEED) {
        // 1) fused: support = bf16(x @ W) via MFMA  ||  bucket histogram
        gcn_gemm_count<<<GEMM_BLKS + ABLK, 512, 0, stream>>>(x, weight, support,
                                                             adj_row, count);
        // 2) scan_a -> scan_b -> bin
        scan_a<<<NSA, 256, 0, stream>>>(count, ptr, bsum);
        scan_b<<<1, 1024, 0, stream>>>(bsum);
        gcn_bin<<<ABLK, 1024, 0, stream>>>(adj_row, adj_col, adj_val, ptr, bsum, rec);
        // 3) per-bucket counting-sort + 4-deep pipelined register gather
        gcn_rows<<<NB, 1024, 0, stream>>>(bsum, rec, support, bias, out);
    } else {
        gcn_gemm_count<<<GEMM_BLKS, 512, 0, stream>>>(x, weight, support,
                                                      adj_row, (int*)ws);  // gemm only
        gcn_bias_init<<<(N_NODES * OUT_F + 255) / 256, 256, 0, stream>>>(bias, out);
        gcn_scatter<<<8192, 256, 0, stream>>>(adj_row, adj_col, adj_val, support, out);
    }
}

// Round 11
// 81.802 us; speedup vs baseline: 4.9232x; 1.0218x over previous
//
#include <hip/hip_runtime.h>
#include <stdint.h>

#define N_NODES 100000
#define N_EDGES 1600000
#define IN_F 128
#define OUT_F 32

#define RB 64                     // rows per bucket (shift 6)
#define NB 1563                   // ceil(N_NODES / RB)
#define ABLK 256                  // bin blocks
#define EPA (N_EDGES / ABLK)      // 6250 edges per bin block (exact)
#define CAP 1536                  // slots per bucket region (mean 1024, 16 sigma)
#define MTILES (N_NODES / 16)     // 6250 row-tiles for MFMA gemm (exact)
#define GEMM_BLKS ((MTILES + 7) / 8)   // 782 gemm blocks (8 waves x 1 tile)

typedef __attribute__((ext_vector_type(8))) short bf16x8;
typedef __attribute__((ext_vector_type(4))) float f32x4;

__device__ __forceinline__ float bf2f(unsigned short u) {
    return __uint_as_float(((uint32_t)u) << 16);
}
__device__ __forceinline__ unsigned short f2bf(float x) {
    const uint32_t b = __float_as_uint(x);
    return (unsigned short)((b + 0x7fffu + ((b >> 16) & 1u)) >> 16);   // RNE
}

// ---------------------------------------------------------------------------
// K0: init bucket cursors to region bases; zero overflow counter.
// ---------------------------------------------------------------------------
__global__ __launch_bounds__(256) void gcn_init(int* __restrict__ cur,
                                                int* __restrict__ ovf_cnt) {
    const int i = blockIdx.x * 256 + threadIdx.x;
    if (i < NB) cur[i] = i * CAP;
    if (i == NB) *ovf_cnt = 0;
}

// ---------------------------------------------------------------------------
// K1 (fused): blocks [0,GEMM_BLKS) do MFMA GEMM; blocks [GEMM_BLKS,+ABLK) do
// bin: LDS histogram -> per-bucket global reservation -> scatter into fixed-
// capacity bucket regions. No scan stage anywhere.
// ---------------------------------------------------------------------------
__global__ __launch_bounds__(512) void gcn_gemm_bin(const float* __restrict__ x,
                                                    const float* __restrict__ w,
                                                    unsigned short* __restrict__ support,
                                                    const int* __restrict__ row,
                                                    const int* __restrict__ col,
                                                    const float* __restrict__ val,
                                                    int* __restrict__ cur,
                                                    int* __restrict__ ovf_cnt,
                                                    long long* __restrict__ rec,
                                                    long long* __restrict__ ovf_pk,
                                                    int* __restrict__ ovf_bk) {
    __shared__ unsigned short wt[OUT_F][IN_F + 8];   // gemm: 8.7 KB
    __shared__ int h[NB];                            // bin:  6.25 KB
    const int tid = threadIdx.x;

    if (blockIdx.x < GEMM_BLKS) {
        // ---------------- GEMM: support = bf16(x @ W) ----------------
        #pragma unroll
        for (int i = tid; i < IN_F * OUT_F; i += 512) {
            const int k = i >> 5, f = i & 31;
            wt[f][k] = f2bf(w[i]);
        }
        __syncthreads();

        const int wv = tid >> 6;                 // wave 0..7
        const int lane = tid & 63;
        const int rowT = blockIdx.x * 8 + wv;    // 16-row tile index
        if (rowT >= MTILES) return;
        const int row0 = rowT * 16;

        const int mrow = lane & 15;              // A row / C col index
        const int kg = lane >> 4;                // k-group 0..3
        const int kb = kg * 8;

        bf16x8 bfrag[4][2];
        #pragma unroll
        for (int ks = 0; ks < 4; ++ks) {
            #pragma unroll
            for (int nt = 0; nt < 2; ++nt) {
                bfrag[ks][nt] = *reinterpret_cast<const bf16x8*>(
                    &wt[mrow + nt * 16][ks * 32 + kb]);
            }
        }

        f32x4 acc0 = {0.f, 0.f, 0.f, 0.f};
        f32x4 acc1 = {0.f, 0.f, 0.f, 0.f};
        const float* xr = &x[(size_t)(row0 + mrow) * IN_F];
        #pragma unroll
        for (int ks = 0; ks < 4; ++ks) {
            const float4 a0 = *reinterpret_cast<const float4*>(&xr[ks * 32 + kb]);
            const float4 a1 = *reinterpret_cast<const float4*>(&xr[ks * 32 + kb + 4]);
            bf16x8 af;
            af[0] = (short)f2bf(a0.x); af[1] = (short)f2bf(a0.y);
            af[2] = (short)f2bf(a0.z); af[3] = (short)f2bf(a0.w);
            af[4] = (short)f2bf(a1.x); af[5] = (short)f2bf(a1.y);
            af[6] = (short)f2bf(a1.z); af[7] = (short)f2bf(a1.w);
            acc0 = __builtin_amdgcn_mfma_f32_16x16x32_bf16(af, bfrag[ks][0], acc0, 0, 0, 0);
            acc1 = __builtin_amdgcn_mfma_f32_16x16x32_bf16(af, bfrag[ks][1], acc1, 0, 0, 0);
        }
        #pragma unroll
        for (int r = 0; r < 4; ++r) {
            const int orow = row0 + kg * 4 + r;
            support[(size_t)orow * OUT_F + mrow]      = f2bf(acc0[r]);
            support[(size_t)orow * OUT_F + mrow + 16] = f2bf(acc1[r]);
        }
    } else {
        // ---------------- BIN: hist -> reserve -> scatter ----------------
        const int b = blockIdx.x - GEMM_BLKS;
        for (int i = tid; i < NB; i += 512) h[i] = 0;
        __syncthreads();
        const int e0 = b * EPA;
        for (int i = tid; i < EPA; i += 512)
            atomicAdd(&h[row[e0 + i] >> 6], 1);
        __syncthreads();
        // reserve a contiguous sub-range per nonzero bucket; h[k] becomes base
        for (int k = tid; k < NB; k += 512) {
            const int c = h[k];
            if (c > 0) h[k] = atomicAdd(&cur[k], c);
        }
        __syncthreads();
        // scatter
        for (int i = tid; i < EPA; i += 512) {
            const int e = e0 + i;
            const int r = row[e];
            const int k = r >> 6;
            const int slot = atomicAdd(&h[k], 1);
            const long long pk = (long long)(((uint64_t)__float_as_uint(val[e]) << 32) |
                      (uint64_t)((uint32_t)col[e] | ((uint32_t)(r & 63) << 17)));
            if (slot < (k + 1) * CAP) {
                rec[slot] = pk;
            } else {                               // statistically never
                const int oi = atomicAdd(ovf_cnt, 1);
                ovf_pk[oi] = pk;
                ovf_bk[oi] = k;
            }
        }
    }
}

// ---------------------------------------------------------------------------
// K2: 1024 threads (32 row-groups x 2 passes), one block per bucket.
// LDS counting-sort to exact row order, then register accumulation with a
// 4-deep unrolled gather pipeline. Bucket span read straight from cur[].
// ---------------------------------------------------------------------------
__global__ __launch_bounds__(1024) void gcn_rows(const int* __restrict__ cur,
                                                 const int* __restrict__ ovf_cnt,
                                                 const long long* __restrict__ rec,
                                                 const long long* __restrict__ ovf_pk,
                                                 const int* __restrict__ ovf_bk,
                                                 const unsigned short* __restrict__ sup,
                                                 const float* __restrict__ bias,
                                                 float* __restrict__ out) {
    __shared__ long long rbuf[CAP];    // 12 KB
    __shared__ long long srt[CAP];     // 12 KB
    __shared__ int cnt[RB];            // reused as cursor after scan
    __shared__ int rs[RB + 1];         // row segment starts
    __shared__ float bs[OUT_F];
    const int tid = threadIdx.x, k = blockIdx.x;

    const int start = k * CAP;
    const int total = cur[k] - start;          // bucket count (incl. spilled)
    const int n = min(total, CAP);             // in-region records
    const int novf = *ovf_cnt;                 // normally 0

    if (tid < OUT_F) bs[tid] = bias[tid];
    if (tid < RB) cnt[tid] = 0;
    for (int i = tid; i < n; i += 1024) rbuf[i] = rec[start + i];   // coalesced stage
    __syncthreads();

    for (int i = tid; i < n; i += 1024)
        atomicAdd(&cnt[(int)(((uint64_t)rbuf[i] >> 17) & 63)], 1);
    __syncthreads();

    if (tid < 64) {      // exclusive scan of 64 counters in wave 0
        const int v = cnt[tid];
        int sc = v;
        #pragma unroll
        for (int d = 1; d < 64; d <<= 1) {
            const int t2 = __shfl_up(sc, d, 64);
            if (tid >= d) sc += t2;
        }
        rs[tid] = sc - v;
        cnt[tid] = sc - v;
        if (tid == 63) rs[64] = sc;
    }
    __syncthreads();

    for (int i = tid; i < n; i += 1024) {       // reorder into exact row order
        const long long pk = rbuf[i];
        const int rl = (int)(((uint64_t)pk >> 17) & 63);
        const int slot = atomicAdd(&cnt[rl], 1);
        srt[slot] = pk;
    }
    __syncthreads();

    // register accumulation: 32 groups x 2 passes = 64 rows
    const int g = tid >> 5;           // row-group 0..31
    const int f = tid & 31;           // feature
    const int rowBase = k * RB;

    for (int rp = 0; rp < 2; ++rp) {
        const int r = rp * 32 + g;
        const int gr = rowBase + r;
        const int s0 = rs[r];
        const int s1 = rs[r + 1];
        float a0 = bs[f], a1 = 0.f, a2 = 0.f, a3 = 0.f;
        int i = s0;
        for (; i + 4 <= s1; i += 4) {
            const uint64_t p0 = (uint64_t)srt[i];
            const uint64_t p1 = (uint64_t)srt[i + 1];
            const uint64_t p2 = (uint64_t)srt[i + 2];
            const uint64_t p3 = (uint64_t)srt[i + 3];
            const unsigned short q0 = sup[(size_t)(p0 & 0x1ffff) * OUT_F + f];
            const unsigned short q1 = sup[(size_t)(p1 & 0x1ffff) * OUT_F + f];
            const unsigned short q2 = sup[(size_t)(p2 & 0x1ffff) * OUT_F + f];
            const unsigned short q3 = sup[(size_t)(p3 & 0x1ffff) * OUT_F + f];
            a0 += __uint_as_float((uint32_t)(p0 >> 32)) * bf2f(q0);
            a1 += __uint_as_float((uint32_t)(p1 >> 32)) * bf2f(q1);
            a2 += __uint_as_float((uint32_t)(p2 >> 32)) * bf2f(q2);
            a3 += __uint_as_float((uint32_t)(p3 >> 32)) * bf2f(q3);
        }
        for (; i < s1; ++i) {
            const uint64_t pk = (uint64_t)srt[i];
            const unsigned short q = sup[(size_t)(pk & 0x1ffff) * OUT_F + f];
            a0 += __uint_as_float((uint32_t)(pk >> 32)) * bf2f(q);
        }
        // overflow list (normally empty; correctness guard)
        for (int j = 0; j < novf; ++j) {
            if (ovf_bk[j] == k) {
                const uint64_t pk = (uint64_t)ovf_pk[j];
                if ((int)((pk >> 17) & 63) == r) {
                    const unsigned short q = sup[(size_t)(pk & 0x1ffff) * OUT_F + f];
                    a0 += __uint_as_float((uint32_t)(pk >> 32)) * bf2f(q);
                }
            }
        }
        if (gr < N_NODES)
            out[(size_t)gr * OUT_F + f] = (a0 + a1) + (a2 + a3);
    }
}

// ---------------------------------------------------------------------------
// Fallback path (ws too small): gemm-only + atomic scatter
// ---------------------------------------------------------------------------
__global__ __launch_bounds__(256) void gcn_bias_init(const float* __restrict__ bias,
                                                     float* __restrict__ out) {
    const int i = blockIdx.x * 256 + threadIdx.x;
    if (i < N_NODES * OUT_F) out[i] = bias[i & 31];
}

__global__ __launch_bounds__(512) void gcn_gemm_only(const float* __restrict__ x,
                                                     const float* __restrict__ w,
                                                     unsigned short* __restrict__ support) {
    __shared__ unsigned short wt[OUT_F][IN_F + 8];
    const int tid = threadIdx.x;
    #pragma unroll
    for (int i = tid; i < IN_F * OUT_F; i += 512) {
        const int k = i >> 5, f = i & 31;
        wt[f][k] = f2bf(w[i]);
    }
    __syncthreads();
    const int wv = tid >> 6;
    const int lane = tid & 63;
    const int rowT = blockIdx.x * 8 + wv;
    if (rowT >= MTILES) return;
    const int row0 = rowT * 16;
    const int mrow = lane & 15;
    const int kg = lane >> 4;
    const int kb = kg * 8;
    bf16x8 bfrag[4][2];
    #pragma unroll
    for (int ks = 0; ks < 4; ++ks)
        #pragma unroll
        for (int nt = 0; nt < 2; ++nt)
            bfrag[ks][nt] = *reinterpret_cast<const bf16x8*>(
                &wt[mrow + nt * 16][ks * 32 + kb]);
    f32x4 acc0 = {0.f, 0.f, 0.f, 0.f};
    f32x4 acc1 = {0.f, 0.f, 0.f, 0.f};
    const float* xr = &x[(size_t)(row0 + mrow) * IN_F];
    #pragma unroll
    for (int ks = 0; ks < 4; ++ks) {
        const float4 a0 = *reinterpret_cast<const float4*>(&xr[ks * 32 + kb]);
        const float4 a1 = *reinterpret_cast<const float4*>(&xr[ks * 32 + kb + 4]);
        bf16x8 af;
        af[0] = (short)f2bf(a0.x); af[1] = (short)f2bf(a0.y);
        af[2] = (short)f2bf(a0.z); af[3] = (short)f2bf(a0.w);
        af[4] = (short)f2bf(a1.x); af[5] = (short)f2bf(a1.y);
        af[6] = (short)f2bf(a1.z); af[7] = (short)f2bf(a1.w);
        acc0 = __builtin_amdgcn_mfma_f32_16x16x32_bf16(af, bfrag[ks][0], acc0, 0, 0, 0);
        acc1 = __builtin_amdgcn_mfma_f32_16x16x32_bf16(af, bfrag[ks][1], acc1, 0, 0, 0);
    }
    #pragma unroll
    for (int r = 0; r < 4; ++r) {
        const int orow = row0 + kg * 4 + r;
        support[(size_t)orow * OUT_F + mrow]      = f2bf(acc0[r]);
        support[(size_t)orow * OUT_F + mrow + 16] = f2bf(acc1[r]);
    }
}

__global__ __launch_bounds__(256) void gcn_scatter(const int* __restrict__ row,
                                                   const int* __restrict__ col,
                                                   const float* __restrict__ val,
                                                   const unsigned short* __restrict__ sup,
                                                   float* __restrict__ out) {
    const int f = threadIdx.x & 31;
    const int grp = threadIdx.x >> 5;
    long long e = (long long)blockIdx.x * 8 + grp;
    const long long stride = (long long)gridDim.x * 8;
    for (; e < N_EDGES; e += stride) {
        const int r = row[e];
        const int c = col[e];
        const float v = val[e];
        const float s = bf2f(sup[(size_t)c * OUT_F + f]);
        atomicAdd(&out[(size_t)r * OUT_F + f], v * s);
    }
}

extern "C" void kernel_launch(void* const* d_in, const int* in_sizes, int n_in,
                              void* d_out, int out_size, void* d_ws, size_t ws_size,
                              hipStream_t stream) {
    const float* x       = (const float*)d_in[0];
    const int*   adj_row = (const int*)d_in[1];
    const int*   adj_col = (const int*)d_in[2];
    const float* adj_val = (const float*)d_in[3];
    const float* weight  = (const float*)d_in[4];
    const float* bias    = (const float*)d_in[5];
    float* out = (float*)d_out;

    char* ws = (char*)d_ws;
    const size_t SUPPORT_B = (((size_t)N_NODES * OUT_F * 2) + 255) & ~(size_t)255;  // 6.4 MB
    const size_t REC_B     = (((size_t)NB * CAP * 8) + 255) & ~(size_t)255;         // 19.2 MB
    const size_t CUR_B     = (((size_t)NB * 4) + 255) & ~(size_t)255;
    const size_t OCN_B     = 256;
    const size_t OPK_B     = (size_t)N_EDGES * 8;                                   // 12.8 MB
    const size_t OBK_B     = (size_t)N_EDGES * 4;                                   // 6.4 MB
    const size_t NEED = SUPPORT_B + REC_B + CUR_B + OCN_B + OPK_B + OBK_B;

    unsigned short* support = (unsigned short*)(ws);
    long long* rec  = (long long*)(ws + SUPPORT_B);
    int* cur        = (int*)(ws + SUPPORT_B + REC_B);
    int* ovf_cnt    = (int*)(ws + SUPPORT_B + REC_B + CUR_B);
    long long* ovf_pk = (long long*)(ws + SUPPORT_B + REC_B + CUR_B + OCN_B);
    int* ovf_bk     = (int*)(ws + SUPPORT_B + REC_B + CUR_B + OCN_B + OPK_B);

    if (ws_size >= NEED) {
        // K0: cursor init
        gcn_init<<<(NB + 256) / 256, 256, 0, stream>>>(cur, ovf_cnt);
        // K1: fused MFMA gemm || bucket bin (hist -> reserve -> scatter)
        gcn_gemm_bin<<<GEMM_BLKS + ABLK, 512, 0, stream>>>(x, weight, support,
                                                           adj_row, adj_col, adj_val,
                                                           cur, ovf_cnt, rec,
                                                           ovf_pk, ovf_bk);
        // K2: per-bucket counting-sort + pipelined register gather
        gcn_rows<<<NB, 1024, 0, stream>>>(cur, ovf_cnt, rec, ovf_pk, ovf_bk,
                                          support, bias, out);
    } else {
        gcn_gemm_only<<<GEMM_BLKS, 512, 0, stream>>>(x, weight, support);
        gcn_bias_init<<<(N_NODES * OUT_F + 255) / 256, 256, 0, stream>>>(bias, out);
        gcn_scatter<<<8192, 256, 0, stream>>>(adj_row, adj_col, adj_val, support, out);
    }
}

// Round 12
// 68.242 us; speedup vs baseline: 5.9014x; 1.1987x over previous
//
#include <hip/hip_runtime.h>
#include <stdint.h>

#define N_NODES 100000
#define N_EDGES 1600000
#define IN_F 128
#define OUT_F 32

#define RB 64                     // rows per bucket (shift 6)
#define NB 1563                   // ceil(N_NODES / RB)
#define BBLK 320                  // bin blocks
#define EPA (N_EDGES / BBLK)      // 5000 edges per bin block (exact)
#define CAP 1536                  // slots per bucket region (mean 1024, 16 sigma)
#define MTILES (N_NODES / 16)     // 6250 row-tiles for MFMA gemm (exact)
#define GEMM_BLKS ((MTILES + 15) / 16)   // 391 gemm blocks (16 waves x 1 tile)

typedef __attribute__((ext_vector_type(8))) short bf16x8;
typedef __attribute__((ext_vector_type(4))) float f32x4;

__device__ __forceinline__ float bf2f(unsigned short u) {
    return __uint_as_float(((uint32_t)u) << 16);
}
__device__ __forceinline__ unsigned short f2bf(float x) {
    const uint32_t b = __float_as_uint(x);
    return (unsigned short)((b + 0x7fffu + ((b >> 16) & 1u)) >> 16);   // RNE
}
__device__ __forceinline__ long long pack_rec(int r, int c, uint32_t v) {
    return (long long)(((uint64_t)v << 32) |
           (uint64_t)((uint32_t)c | ((uint32_t)(r & 63) << 17)));
}

// ---------------------------------------------------------------------------
// K0: init bucket cursors to region bases; zero overflow counter.
// ---------------------------------------------------------------------------
__global__ __launch_bounds__(256) void gcn_init(int* __restrict__ cur,
                                                int* __restrict__ ovf_cnt) {
    const int i = blockIdx.x * 256 + threadIdx.x;
    if (i < NB) cur[i] = i * CAP;
    if (i == NB) *ovf_cnt = 0;
}

// ---------------------------------------------------------------------------
// K1 (fused, 1024 thr): blocks [0,GEMM_BLKS) = MFMA GEMM (16 tiles/block);
// blocks [GEMM_BLKS,+BBLK) = bin: LDS hist -> per-bucket atomic reservation ->
// 4-deep batched scatter into fixed-capacity bucket regions.
// ---------------------------------------------------------------------------
__global__ __launch_bounds__(1024) void gcn_gemm_bin(const float* __restrict__ x,
                                                     const float* __restrict__ w,
                                                     unsigned short* __restrict__ support,
                                                     const int* __restrict__ row,
                                                     const int* __restrict__ col,
                                                     const float* __restrict__ val,
                                                     int* __restrict__ cur,
                                                     int* __restrict__ ovf_cnt,
                                                     long long* __restrict__ rec,
                                                     long long* __restrict__ ovf_pk,
                                                     int* __restrict__ ovf_bk) {
    __shared__ unsigned short wt[OUT_F][IN_F + 8];   // gemm: 8.7 KB
    __shared__ int h[NB];                            // bin:  6.25 KB
    const int tid = threadIdx.x;

    if (blockIdx.x < GEMM_BLKS) {
        // ---------------- GEMM: support = bf16(x @ W) ----------------
        #pragma unroll
        for (int i = tid; i < IN_F * OUT_F; i += 1024) {
            const int k = i >> 5, f = i & 31;
            wt[f][k] = f2bf(w[i]);
        }
        __syncthreads();

        const int wv = tid >> 6;                 // wave 0..15
        const int lane = tid & 63;
        const int rowT = blockIdx.x * 16 + wv;   // 16-row tile index
        if (rowT >= MTILES) return;
        const int row0 = rowT * 16;

        const int mrow = lane & 15;              // A row / C col index
        const int kg = lane >> 4;                // k-group 0..3
        const int kb = kg * 8;

        bf16x8 bfrag[4][2];
        #pragma unroll
        for (int ks = 0; ks < 4; ++ks) {
            #pragma unroll
            for (int nt = 0; nt < 2; ++nt) {
                bfrag[ks][nt] = *reinterpret_cast<const bf16x8*>(
                    &wt[mrow + nt * 16][ks * 32 + kb]);
            }
        }

        f32x4 acc0 = {0.f, 0.f, 0.f, 0.f};
        f32x4 acc1 = {0.f, 0.f, 0.f, 0.f};
        const float* xr = &x[(size_t)(row0 + mrow) * IN_F];
        #pragma unroll
        for (int ks = 0; ks < 4; ++ks) {
            const float4 a0 = *reinterpret_cast<const float4*>(&xr[ks * 32 + kb]);
            const float4 a1 = *reinterpret_cast<const float4*>(&xr[ks * 32 + kb + 4]);
            bf16x8 af;
            af[0] = (short)f2bf(a0.x); af[1] = (short)f2bf(a0.y);
            af[2] = (short)f2bf(a0.z); af[3] = (short)f2bf(a0.w);
            af[4] = (short)f2bf(a1.x); af[5] = (short)f2bf(a1.y);
            af[6] = (short)f2bf(a1.z); af[7] = (short)f2bf(a1.w);
            acc0 = __builtin_amdgcn_mfma_f32_16x16x32_bf16(af, bfrag[ks][0], acc0, 0, 0, 0);
            acc1 = __builtin_amdgcn_mfma_f32_16x16x32_bf16(af, bfrag[ks][1], acc1, 0, 0, 0);
        }
        #pragma unroll
        for (int r = 0; r < 4; ++r) {
            const int orow = row0 + kg * 4 + r;
            support[(size_t)orow * OUT_F + mrow]      = f2bf(acc0[r]);
            support[(size_t)orow * OUT_F + mrow + 16] = f2bf(acc1[r]);
        }
    } else {
        // ---------------- BIN: hist -> reserve -> scatter ----------------
        const int b = blockIdx.x - GEMM_BLKS;
        for (int i = tid; i < NB; i += 1024) h[i] = 0;
        __syncthreads();
        const int e0 = b * EPA;

        // hist, 4-deep batched (tid+3072 <= 4095 < EPA always)
        {
            const int r0 = row[e0 + tid];
            const int r1 = row[e0 + tid + 1024];
            const int r2 = row[e0 + tid + 2048];
            const int r3 = row[e0 + tid + 3072];
            atomicAdd(&h[r0 >> 6], 1);
            atomicAdd(&h[r1 >> 6], 1);
            atomicAdd(&h[r2 >> 6], 1);
            atomicAdd(&h[r3 >> 6], 1);
            const int i4 = tid + 4096;
            if (i4 < EPA) atomicAdd(&h[row[e0 + i4] >> 6], 1);
        }
        __syncthreads();
        // reserve a contiguous sub-range per nonzero bucket; h[k] becomes base
        for (int k = tid; k < NB; k += 1024) {
            const int c = h[k];
            if (c > 0) h[k] = atomicAdd(&cur[k], c);
        }
        __syncthreads();
        // scatter, 4-deep batched
        {
            const int r0 = row[e0 + tid];
            const int r1 = row[e0 + tid + 1024];
            const int r2 = row[e0 + tid + 2048];
            const int r3 = row[e0 + tid + 3072];
            const int c0 = col[e0 + tid];
            const int c1 = col[e0 + tid + 1024];
            const int c2 = col[e0 + tid + 2048];
            const int c3 = col[e0 + tid + 3072];
            const uint32_t v0 = __float_as_uint(val[e0 + tid]);
            const uint32_t v1 = __float_as_uint(val[e0 + tid + 1024]);
            const uint32_t v2 = __float_as_uint(val[e0 + tid + 2048]);
            const uint32_t v3 = __float_as_uint(val[e0 + tid + 3072]);
            const int k0 = r0 >> 6, k1 = r1 >> 6, k2 = r2 >> 6, k3 = r3 >> 6;
            const int s0 = atomicAdd(&h[k0], 1);
            const int s1 = atomicAdd(&h[k1], 1);
            const int s2 = atomicAdd(&h[k2], 1);
            const int s3 = atomicAdd(&h[k3], 1);
            const long long p0 = pack_rec(r0, c0, v0);
            const long long p1 = pack_rec(r1, c1, v1);
            const long long p2 = pack_rec(r2, c2, v2);
            const long long p3 = pack_rec(r3, c3, v3);
            if (s0 < (k0 + 1) * CAP) rec[s0] = p0;
            else { const int oi = atomicAdd(ovf_cnt, 1); ovf_pk[oi] = p0; ovf_bk[oi] = k0; }
            if (s1 < (k1 + 1) * CAP) rec[s1] = p1;
            else { const int oi = atomicAdd(ovf_cnt, 1); ovf_pk[oi] = p1; ovf_bk[oi] = k1; }
            if (s2 < (k2 + 1) * CAP) rec[s2] = p2;
            else { const int oi = atomicAdd(ovf_cnt, 1); ovf_pk[oi] = p2; ovf_bk[oi] = k2; }
            if (s3 < (k3 + 1) * CAP) rec[s3] = p3;
            else { const int oi = atomicAdd(ovf_cnt, 1); ovf_pk[oi] = p3; ovf_bk[oi] = k3; }
            const int i4 = tid + 4096;
            if (i4 < EPA) {
                const int e = e0 + i4;
                const int r = row[e];
                const int k = r >> 6;
                const int slot = atomicAdd(&h[k], 1);
                const long long pk = pack_rec(r, col[e], __float_as_uint(val[e]));
                if (slot < (k + 1) * CAP) rec[slot] = pk;
                else { const int oi = atomicAdd(ovf_cnt, 1); ovf_pk[oi] = pk; ovf_bk[oi] = k; }
            }
        }
    }
}

// ---------------------------------------------------------------------------
// K2: 1024 threads (32 row-groups x 2 passes), one block per bucket.
// LDS counting-sort to exact row order, then register accumulation with a
// 4-deep unrolled gather pipeline. Bucket span read straight from cur[].
// ---------------------------------------------------------------------------
__global__ __launch_bounds__(1024) void gcn_rows(const int* __restrict__ cur,
                                                 const int* __restrict__ ovf_cnt,
                                                 const long long* __restrict__ rec,
                                                 const long long* __restrict__ ovf_pk,
                                                 const int* __restrict__ ovf_bk,
                                                 const unsigned short* __restrict__ sup,
                                                 const float* __restrict__ bias,
                                                 float* __restrict__ out) {
    __shared__ long long rbuf[CAP];    // 12 KB
    __shared__ long long srt[CAP];     // 12 KB
    __shared__ int cnt[RB];            // reused as cursor after scan
    __shared__ int rs[RB + 1];         // row segment starts
    __shared__ float bs[OUT_F];
    const int tid = threadIdx.x, k = blockIdx.x;

    const int start = k * CAP;
    const int total = cur[k] - start;          // bucket count (incl. spilled)
    const int n = min(total, CAP);             // in-region records
    const int novf = *ovf_cnt;                 // normally 0

    if (tid < OUT_F) bs[tid] = bias[tid];
    if (tid < RB) cnt[tid] = 0;
    for (int i = tid; i < n; i += 1024) rbuf[i] = rec[start + i];   // coalesced stage
    __syncthreads();

    for (int i = tid; i < n; i += 1024)
        atomicAdd(&cnt[(int)(((uint64_t)rbuf[i] >> 17) & 63)], 1);
    __syncthreads();

    if (tid < 64) {      // exclusive scan of 64 counters in wave 0
        const int v = cnt[tid];
        int sc = v;
        #pragma unroll
        for (int d = 1; d < 64; d <<= 1) {
            const int t2 = __shfl_up(sc, d, 64);
            if (tid >= d) sc += t2;
        }
        rs[tid] = sc - v;
        cnt[tid] = sc - v;
        if (tid == 63) rs[64] = sc;
    }
    __syncthreads();

    for (int i = tid; i < n; i += 1024) {       // reorder into exact row order
        const long long pk = rbuf[i];
        const int rl = (int)(((uint64_t)pk >> 17) & 63);
        const int slot = atomicAdd(&cnt[rl], 1);
        srt[slot] = pk;
    }
    __syncthreads();

    // register accumulation: 32 groups x 2 passes = 64 rows
    const int g = tid >> 5;           // row-group 0..31
    const int f = tid & 31;           // feature
    const int rowBase = k * RB;

    for (int rp = 0; rp < 2; ++rp) {
        const int r = rp * 32 + g;
        const int gr = rowBase + r;
        const int s0 = rs[r];
        const int s1 = rs[r + 1];
        float a0 = bs[f], a1 = 0.f, a2 = 0.f, a3 = 0.f;
        int i = s0;
        for (; i + 4 <= s1; i += 4) {
            const uint64_t p0 = (uint64_t)srt[i];
            const uint64_t p1 = (uint64_t)srt[i + 1];
            const uint64_t p2 = (uint64_t)srt[i + 2];
            const uint64_t p3 = (uint64_t)srt[i + 3];
            const unsigned short q0 = sup[(size_t)(p0 & 0x1ffff) * OUT_F + f];
            const unsigned short q1 = sup[(size_t)(p1 & 0x1ffff) * OUT_F + f];
            const unsigned short q2 = sup[(size_t)(p2 & 0x1ffff) * OUT_F + f];
            const unsigned short q3 = sup[(size_t)(p3 & 0x1ffff) * OUT_F + f];
            a0 += __uint_as_float((uint32_t)(p0 >> 32)) * bf2f(q0);
            a1 += __uint_as_float((uint32_t)(p1 >> 32)) * bf2f(q1);
            a2 += __uint_as_float((uint32_t)(p2 >> 32)) * bf2f(q2);
            a3 += __uint_as_float((uint32_t)(p3 >> 32)) * bf2f(q3);
        }
        for (; i < s1; ++i) {
            const uint64_t pk = (uint64_t)srt[i];
            const unsigned short q = sup[(size_t)(pk & 0x1ffff) * OUT_F + f];
            a0 += __uint_as_float((uint32_t)(pk >> 32)) * bf2f(q);
        }
        // overflow list (normally empty; correctness guard)
        for (int j = 0; j < novf; ++j) {
            if (ovf_bk[j] == k) {
                const uint64_t pk = (uint64_t)ovf_pk[j];
                if ((int)((pk >> 17) & 63) == r) {
                    const unsigned short q = sup[(size_t)(pk & 0x1ffff) * OUT_F + f];
                    a0 += __uint_as_float((uint32_t)(pk >> 32)) * bf2f(q);
                }
            }
        }
        if (gr < N_NODES)
            out[(size_t)gr * OUT_F + f] = (a0 + a1) + (a2 + a3);
    }
}

// ---------------------------------------------------------------------------
// Fallback path (ws too small): gemm-only + atomic scatter
// ---------------------------------------------------------------------------
__global__ __launch_bounds__(256) void gcn_bias_init(const float* __restrict__ bias,
                                                     float* __restrict__ out) {
    const int i = blockIdx.x * 256 + threadIdx.x;
    if (i < N_NODES * OUT_F) out[i] = bias[i & 31];
}

__global__ __launch_bounds__(512) void gcn_gemm_only(const float* __restrict__ x,
                                                     const float* __restrict__ w,
                                                     unsigned short* __restrict__ support) {
    __shared__ unsigned short wt[OUT_F][IN_F + 8];
    const int tid = threadIdx.x;
    #pragma unroll
    for (int i = tid; i < IN_F * OUT_F; i += 512) {
        const int k = i >> 5, f = i & 31;
        wt[f][k] = f2bf(w[i]);
    }
    __syncthreads();
    const int wv = tid >> 6;
    const int lane = tid & 63;
    const int rowT = blockIdx.x * 8 + wv;
    if (rowT >= MTILES) return;
    const int row0 = rowT * 16;
    const int mrow = lane & 15;
    const int kg = lane >> 4;
    const int kb = kg * 8;
    bf16x8 bfrag[4][2];
    #pragma unroll
    for (int ks = 0; ks < 4; ++ks)
        #pragma unroll
        for (int nt = 0; nt < 2; ++nt)
            bfrag[ks][nt] = *reinterpret_cast<const bf16x8*>(
                &wt[mrow + nt * 16][ks * 32 + kb]);
    f32x4 acc0 = {0.f, 0.f, 0.f, 0.f};
    f32x4 acc1 = {0.f, 0.f, 0.f, 0.f};
    const float* xr = &x[(size_t)(row0 + mrow) * IN_F];
    #pragma unroll
    for (int ks = 0; ks < 4; ++ks) {
        const float4 a0 = *reinterpret_cast<const float4*>(&xr[ks * 32 + kb]);
        const float4 a1 = *reinterpret_cast<const float4*>(&xr[ks * 32 + kb + 4]);
        bf16x8 af;
        af[0] = (short)f2bf(a0.x); af[1] = (short)f2bf(a0.y);
        af[2] = (short)f2bf(a0.z); af[3] = (short)f2bf(a0.w);
        af[4] = (short)f2bf(a1.x); af[5] = (short)f2bf(a1.y);
        af[6] = (short)f2bf(a1.z); af[7] = (short)f2bf(a1.w);
        acc0 = __builtin_amdgcn_mfma_f32_16x16x32_bf16(af, bfrag[ks][0], acc0, 0, 0, 0);
        acc1 = __builtin_amdgcn_mfma_f32_16x16x32_bf16(af, bfrag[ks][1], acc1, 0, 0, 0);
    }
    #pragma unroll
    for (int r = 0; r < 4; ++r) {
        const int orow = row0 + kg * 4 + r;
        support[(size_t)orow * OUT_F + mrow]      = f2bf(acc0[r]);
        support[(size_t)orow * OUT_F + mrow + 16] = f2bf(acc1[r]);
    }
}

__global__ __launch_bounds__(256) void gcn_scatter(const int* __restrict__ row,
                                                   const int* __restrict__ col,
                                                   const float* __restrict__ val,
                                                   const unsigned short* __restrict__ sup,
                                                   float* __restrict__ out) {
    const int f = threadIdx.x & 31;
    const int grp = threadIdx.x >> 5;
    long long e = (long long)blockIdx.x * 8 + grp;
    const long long stride = (long long)gridDim.x * 8;
    for (; e < N_EDGES; e += stride) {
        const int r = row[e];
        const int c = col[e];
        const float v = val[e];
        const float s = bf2f(sup[(size_t)c * OUT_F + f]);
        atomicAdd(&out[(size_t)r * OUT_F + f], v * s);
    }
}

extern "C" void kernel_launch(void* const* d_in, const int* in_sizes, int n_in,
                              void* d_out, int out_size, void* d_ws, size_t ws_size,
                              hipStream_t stream) {
    const float* x       = (const float*)d_in[0];
    const int*   adj_row = (const int*)d_in[1];
    const int*   adj_col = (const int*)d_in[2];
    const float* adj_val = (const float*)d_in[3];
    const float* weight  = (const float*)d_in[4];
    const float* bias    = (const float*)d_in[5];
    float* out = (float*)d_out;

    char* ws = (char*)d_ws;
    const size_t SUPPORT_B = (((size_t)N_NODES * OUT_F * 2) + 255) & ~(size_t)255;  // 6.4 MB
    const size_t REC_B     = (((size_t)NB * CAP * 8) + 255) & ~(size_t)255;         // 19.2 MB
    const size_t CUR_B     = (((size_t)NB * 4) + 255) & ~(size_t)255;
    const size_t OCN_B     = 256;
    const size_t OPK_B     = (size_t)N_EDGES * 8;                                   // 12.8 MB
    const size_t OBK_B     = (size_t)N_EDGES * 4;                                   // 6.4 MB
    const size_t NEED = SUPPORT_B + REC_B + CUR_B + OCN_B + OPK_B + OBK_B;

    unsigned short* support = (unsigned short*)(ws);
    long long* rec  = (long long*)(ws + SUPPORT_B);
    int* cur        = (int*)(ws + SUPPORT_B + REC_B);
    int* ovf_cnt    = (int*)(ws + SUPPORT_B + REC_B + CUR_B);
    long long* ovf_pk = (long long*)(ws + SUPPORT_B + REC_B + CUR_B + OCN_B);
    int* ovf_bk     = (int*)(ws + SUPPORT_B + REC_B + CUR_B + OCN_B + OPK_B);

    if (ws_size >= NEED) {
        // K0: cursor init
        gcn_init<<<(NB + 256) / 256, 256, 0, stream>>>(cur, ovf_cnt);
        // K1: fused MFMA gemm || bucket bin (hist -> reserve -> batched scatter)
        gcn_gemm_bin<<<GEMM_BLKS + BBLK, 1024, 0, stream>>>(x, weight, support,
                                                            adj_row, adj_col, adj_val,
                                                            cur, ovf_cnt, rec,
                                                            ovf_pk, ovf_bk);
        // K2: per-bucket counting-sort + pipelined register gather
        gcn_rows<<<NB, 1024, 0, stream>>>(cur, ovf_cnt, rec, ovf_pk, ovf_bk,
                                          support, bias, out);
    } else {
        gcn_gemm_only<<<(MTILES + 7) / 8, 512, 0, stream>>>(x, weight, support);
        gcn_bias_init<<<(N_NODES * OUT_F + 255) / 256, 256, 0, stream>>>(bias, out);
        gcn_scatter<<<8192, 256, 0, stream>>>(adj_row, adj_col, adj_val, support, out);
    }
}

// Round 13
// 67.224 us; speedup vs baseline: 5.9908x; 1.0152x over previous
//
#include <hip/hip_runtime.h>
#include <stdint.h>

#define N_NODES 100000
#define N_EDGES 1600000
#define IN_F 128
#define OUT_F 32

#define RB 64                     // rows per bucket (shift 6)
#define NB 1563                   // ceil(N_NODES / RB)
#define BBLK 320                  // bin blocks
#define EPA (N_EDGES / BBLK)      // 5000 edges per bin block (exact)
#define CAP 1536                  // slots per bucket region (mean 1024, 16 sigma)
#define MTILES (N_NODES / 16)     // 6250 row-tiles for MFMA gemm (exact)
#define GEMM_BLKS ((MTILES + 15) / 16)   // 391 gemm blocks (16 waves x 1 tile)

typedef __attribute__((ext_vector_type(8))) short bf16x8;
typedef __attribute__((ext_vector_type(4))) float f32x4;

__device__ __forceinline__ float bf2f(unsigned short u) {
    return __uint_as_float(((uint32_t)u) << 16);
}
__device__ __forceinline__ unsigned short f2bf(float x) {
    const uint32_t b = __float_as_uint(x);
    return (unsigned short)((b + 0x7fffu + ((b >> 16) & 1u)) >> 16);   // RNE
}
__device__ __forceinline__ long long pack_rec(int r, int c, uint32_t v) {
    return (long long)(((uint64_t)v << 32) |
           (uint64_t)((uint32_t)c | ((uint32_t)(r & 63) << 17)));
}

// ---------------------------------------------------------------------------
// K0: init bucket cursors to region bases; zero overflow counter.
// ---------------------------------------------------------------------------
__global__ __launch_bounds__(256) void gcn_init(int* __restrict__ cur,
                                                int* __restrict__ ovf_cnt) {
    const int i = blockIdx.x * 256 + threadIdx.x;
    if (i < NB) cur[i] = i * CAP;
    if (i == NB) *ovf_cnt = 0;
}

// ---------------------------------------------------------------------------
// K1 (fused, 1024 thr): blocks [0,GEMM_BLKS) = MFMA GEMM (16 tiles/block);
// blocks [GEMM_BLKS,+BBLK) = bin with REGISTER-RESIDENT edges:
// single global read of (row,col,val) into 5 named register sets, LDS hist,
// per-bucket atomic reservation, then register->rec scatter (no re-read).
// ---------------------------------------------------------------------------
__global__ __launch_bounds__(1024) void gcn_gemm_bin(const float* __restrict__ x,
                                                     const float* __restrict__ w,
                                                     unsigned short* __restrict__ support,
                                                     const int* __restrict__ row,
                                                     const int* __restrict__ col,
                                                     const float* __restrict__ val,
                                                     int* __restrict__ cur,
                                                     int* __restrict__ ovf_cnt,
                                                     long long* __restrict__ rec,
                                                     long long* __restrict__ ovf_pk,
                                                     int* __restrict__ ovf_bk) {
    __shared__ unsigned short wt[OUT_F][IN_F + 8];   // gemm: 8.7 KB
    __shared__ int h[NB];                            // bin:  6.25 KB
    const int tid = threadIdx.x;

    if (blockIdx.x < GEMM_BLKS) {
        // ---------------- GEMM: support = bf16(x @ W) ----------------
        #pragma unroll
        for (int i = tid; i < IN_F * OUT_F; i += 1024) {
            const int k = i >> 5, f = i & 31;
            wt[f][k] = f2bf(w[i]);
        }
        __syncthreads();

        const int wv = tid >> 6;                 // wave 0..15
        const int lane = tid & 63;
        const int rowT = blockIdx.x * 16 + wv;   // 16-row tile index
        if (rowT >= MTILES) return;
        const int row0 = rowT * 16;

        const int mrow = lane & 15;              // A row / C col index
        const int kg = lane >> 4;                // k-group 0..3
        const int kb = kg * 8;

        bf16x8 bfrag[4][2];
        #pragma unroll
        for (int ks = 0; ks < 4; ++ks) {
            #pragma unroll
            for (int nt = 0; nt < 2; ++nt) {
                bfrag[ks][nt] = *reinterpret_cast<const bf16x8*>(
                    &wt[mrow + nt * 16][ks * 32 + kb]);
            }
        }

        f32x4 acc0 = {0.f, 0.f, 0.f, 0.f};
        f32x4 acc1 = {0.f, 0.f, 0.f, 0.f};
        const float* xr = &x[(size_t)(row0 + mrow) * IN_F];
        #pragma unroll
        for (int ks = 0; ks < 4; ++ks) {
            const float4 a0 = *reinterpret_cast<const float4*>(&xr[ks * 32 + kb]);
            const float4 a1 = *reinterpret_cast<const float4*>(&xr[ks * 32 + kb + 4]);
            bf16x8 af;
            af[0] = (short)f2bf(a0.x); af[1] = (short)f2bf(a0.y);
            af[2] = (short)f2bf(a0.z); af[3] = (short)f2bf(a0.w);
            af[4] = (short)f2bf(a1.x); af[5] = (short)f2bf(a1.y);
            af[6] = (short)f2bf(a1.z); af[7] = (short)f2bf(a1.w);
            acc0 = __builtin_amdgcn_mfma_f32_16x16x32_bf16(af, bfrag[ks][0], acc0, 0, 0, 0);
            acc1 = __builtin_amdgcn_mfma_f32_16x16x32_bf16(af, bfrag[ks][1], acc1, 0, 0, 0);
        }
        #pragma unroll
        for (int r = 0; r < 4; ++r) {
            const int orow = row0 + kg * 4 + r;
            support[(size_t)orow * OUT_F + mrow]      = f2bf(acc0[r]);
            support[(size_t)orow * OUT_F + mrow + 16] = f2bf(acc1[r]);
        }
    } else {
        // -------- BIN: reg-resident load -> hist -> reserve -> scatter --------
        const int b = blockIdx.x - GEMM_BLKS;
        for (int i = tid; i < NB; i += 1024) h[i] = 0;
        __syncthreads();
        const int e0 = b * EPA;
        const int i4 = tid + 4096;
        const bool has4 = (i4 < EPA);            // EPA=5000: true for tid<904

        // single global read of this thread's ~5 edges into named registers
        const int r0 = row[e0 + tid];
        const int r1 = row[e0 + tid + 1024];
        const int r2 = row[e0 + tid + 2048];
        const int r3 = row[e0 + tid + 3072];
        const int r4 = has4 ? row[e0 + i4] : 0;
        const int c0 = col[e0 + tid];
        const int c1 = col[e0 + tid + 1024];
        const int c2 = col[e0 + tid + 2048];
        const int c3 = col[e0 + tid + 3072];
        const int c4 = has4 ? col[e0 + i4] : 0;
        const uint32_t v0 = __float_as_uint(val[e0 + tid]);
        const uint32_t v1 = __float_as_uint(val[e0 + tid + 1024]);
        const uint32_t v2 = __float_as_uint(val[e0 + tid + 2048]);
        const uint32_t v3 = __float_as_uint(val[e0 + tid + 3072]);
        const uint32_t v4 = has4 ? __float_as_uint(val[e0 + i4]) : 0u;

        const int k0 = r0 >> 6, k1 = r1 >> 6, k2 = r2 >> 6,
                  k3 = r3 >> 6, k4 = r4 >> 6;

        // hist
        atomicAdd(&h[k0], 1);
        atomicAdd(&h[k1], 1);
        atomicAdd(&h[k2], 1);
        atomicAdd(&h[k3], 1);
        if (has4) atomicAdd(&h[k4], 1);
        __syncthreads();
        // reserve contiguous sub-range per nonzero bucket; h[k] becomes cursor
        for (int k = tid; k < NB; k += 1024) {
            const int c = h[k];
            if (c > 0) h[k] = atomicAdd(&cur[k], c);
        }
        __syncthreads();
        // scatter straight from registers
        const int s0 = atomicAdd(&h[k0], 1);
        const int s1 = atomicAdd(&h[k1], 1);
        const int s2 = atomicAdd(&h[k2], 1);
        const int s3 = atomicAdd(&h[k3], 1);
        const long long p0 = pack_rec(r0, c0, v0);
        const long long p1 = pack_rec(r1, c1, v1);
        const long long p2 = pack_rec(r2, c2, v2);
        const long long p3 = pack_rec(r3, c3, v3);
        if (s0 < (k0 + 1) * CAP) rec[s0] = p0;
        else { const int oi = atomicAdd(ovf_cnt, 1); ovf_pk[oi] = p0; ovf_bk[oi] = k0; }
        if (s1 < (k1 + 1) * CAP) rec[s1] = p1;
        else { const int oi = atomicAdd(ovf_cnt, 1); ovf_pk[oi] = p1; ovf_bk[oi] = k1; }
        if (s2 < (k2 + 1) * CAP) rec[s2] = p2;
        else { const int oi = atomicAdd(ovf_cnt, 1); ovf_pk[oi] = p2; ovf_bk[oi] = k2; }
        if (s3 < (k3 + 1) * CAP) rec[s3] = p3;
        else { const int oi = atomicAdd(ovf_cnt, 1); ovf_pk[oi] = p3; ovf_bk[oi] = k3; }
        if (has4) {
            const int s4 = atomicAdd(&h[k4], 1);
            const long long p4 = pack_rec(r4, c4, v4);
            if (s4 < (k4 + 1) * CAP) rec[s4] = p4;
            else { const int oi = atomicAdd(ovf_cnt, 1); ovf_pk[oi] = p4; ovf_bk[oi] = k4; }
        }
    }
}

// ---------------------------------------------------------------------------
// K2: 1024 threads (32 row-groups x 2 passes), one block per bucket.
// LDS counting-sort to exact row order, then register accumulation with a
// 4-deep unrolled gather pipeline. Bucket span read straight from cur[].
// ---------------------------------------------------------------------------
__global__ __launch_bounds__(1024) void gcn_rows(const int* __restrict__ cur,
                                                 const int* __restrict__ ovf_cnt,
                                                 const long long* __restrict__ rec,
                                                 const long long* __restrict__ ovf_pk,
                                                 const int* __restrict__ ovf_bk,
                                                 const unsigned short* __restrict__ sup,
                                                 const float* __restrict__ bias,
                                                 float* __restrict__ out) {
    __shared__ long long rbuf[CAP];    // 12 KB
    __shared__ long long srt[CAP];     // 12 KB
    __shared__ int cnt[RB];            // reused as cursor after scan
    __shared__ int rs[RB + 1];         // row segment starts
    __shared__ float bs[OUT_F];
    const int tid = threadIdx.x, k = blockIdx.x;

    const int start = k * CAP;
    const int total = cur[k] - start;          // bucket count (incl. spilled)
    const int n = min(total, CAP);             // in-region records
    const int novf = *ovf_cnt;                 // normally 0

    if (tid < OUT_F) bs[tid] = bias[tid];
    if (tid < RB) cnt[tid] = 0;
    for (int i = tid; i < n; i += 1024) rbuf[i] = rec[start + i];   // coalesced stage
    __syncthreads();

    for (int i = tid; i < n; i += 1024)
        atomicAdd(&cnt[(int)(((uint64_t)rbuf[i] >> 17) & 63)], 1);
    __syncthreads();

    if (tid < 64) {      // exclusive scan of 64 counters in wave 0
        const int v = cnt[tid];
        int sc = v;
        #pragma unroll
        for (int d = 1; d < 64; d <<= 1) {
            const int t2 = __shfl_up(sc, d, 64);
            if (tid >= d) sc += t2;
        }
        rs[tid] = sc - v;
        cnt[tid] = sc - v;
        if (tid == 63) rs[64] = sc;
    }
    __syncthreads();

    for (int i = tid; i < n; i += 1024) {       // reorder into exact row order
        const long long pk = rbuf[i];
        const int rl = (int)(((uint64_t)pk >> 17) & 63);
        const int slot = atomicAdd(&cnt[rl], 1);
        srt[slot] = pk;
    }
    __syncthreads();

    // register accumulation: 32 groups x 2 passes = 64 rows
    const int g = tid >> 5;           // row-group 0..31
    const int f = tid & 31;           // feature
    const int rowBase = k * RB;

    for (int rp = 0; rp < 2; ++rp) {
        const int r = rp * 32 + g;
        const int gr = rowBase + r;
        const int s0 = rs[r];
        const int s1 = rs[r + 1];
        float a0 = bs[f], a1 = 0.f, a2 = 0.f, a3 = 0.f;
        int i = s0;
        for (; i + 4 <= s1; i += 4) {
            const uint64_t p0 = (uint64_t)srt[i];
            const uint64_t p1 = (uint64_t)srt[i + 1];
            const uint64_t p2 = (uint64_t)srt[i + 2];
            const uint64_t p3 = (uint64_t)srt[i + 3];
            const unsigned short q0 = sup[(size_t)(p0 & 0x1ffff) * OUT_F + f];
            const unsigned short q1 = sup[(size_t)(p1 & 0x1ffff) * OUT_F + f];
            const unsigned short q2 = sup[(size_t)(p2 & 0x1ffff) * OUT_F + f];
            const unsigned short q3 = sup[(size_t)(p3 & 0x1ffff) * OUT_F + f];
            a0 += __uint_as_float((uint32_t)(p0 >> 32)) * bf2f(q0);
            a1 += __uint_as_float((uint32_t)(p1 >> 32)) * bf2f(q1);
            a2 += __uint_as_float((uint32_t)(p2 >> 32)) * bf2f(q2);
            a3 += __uint_as_float((uint32_t)(p3 >> 32)) * bf2f(q3);
        }
        for (; i < s1; ++i) {
            const uint64_t pk = (uint64_t)srt[i];
            const unsigned short q = sup[(size_t)(pk & 0x1ffff) * OUT_F + f];
            a0 += __uint_as_float((uint32_t)(pk >> 32)) * bf2f(q);
        }
        // overflow list (normally empty; correctness guard)
        for (int j = 0; j < novf; ++j) {
            if (ovf_bk[j] == k) {
                const uint64_t pk = (uint64_t)ovf_pk[j];
                if ((int)((pk >> 17) & 63) == r) {
                    const unsigned short q = sup[(size_t)(pk & 0x1ffff) * OUT_F + f];
                    a0 += __uint_as_float((uint32_t)(pk >> 32)) * bf2f(q);
                }
            }
        }
        if (gr < N_NODES)
            out[(size_t)gr * OUT_F + f] = (a0 + a1) + (a2 + a3);
    }
}

// ---------------------------------------------------------------------------
// Fallback path (ws too small): gemm-only + atomic scatter
// ---------------------------------------------------------------------------
__global__ __launch_bounds__(256) void gcn_bias_init(const float* __restrict__ bias,
                                                     float* __restrict__ out) {
    const int i = blockIdx.x * 256 + threadIdx.x;
    if (i < N_NODES * OUT_F) out[i] = bias[i & 31];
}

__global__ __launch_bounds__(512) void gcn_gemm_only(const float* __restrict__ x,
                                                     const float* __restrict__ w,
                                                     unsigned short* __restrict__ support) {
    __shared__ unsigned short wt[OUT_F][IN_F + 8];
    const int tid = threadIdx.x;
    #pragma unroll
    for (int i = tid; i < IN_F * OUT_F; i += 512) {
        const int k = i >> 5, f = i & 31;
        wt[f][k] = f2bf(w[i]);
    }
    __syncthreads();
    const int wv = tid >> 6;
    const int lane = tid & 63;
    const int rowT = blockIdx.x * 8 + wv;
    if (rowT >= MTILES) return;
    const int row0 = rowT * 16;
    const int mrow = lane & 15;
    const int kg = lane >> 4;
    const int kb = kg * 8;
    bf16x8 bfrag[4][2];
    #pragma unroll
    for (int ks = 0; ks < 4; ++ks)
        #pragma unroll
        for (int nt = 0; nt < 2; ++nt)
            bfrag[ks][nt] = *reinterpret_cast<const bf16x8*>(
                &wt[mrow + nt * 16][ks * 32 + kb]);
    f32x4 acc0 = {0.f, 0.f, 0.f, 0.f};
    f32x4 acc1 = {0.f, 0.f, 0.f, 0.f};
    const float* xr = &x[(size_t)(row0 + mrow) * IN_F];
    #pragma unroll
    for (int ks = 0; ks < 4; ++ks) {
        const float4 a0 = *reinterpret_cast<const float4*>(&xr[ks * 32 + kb]);
        const float4 a1 = *reinterpret_cast<const float4*>(&xr[ks * 32 + kb + 4]);
        bf16x8 af;
        af[0] = (short)f2bf(a0.x); af[1] = (short)f2bf(a0.y);
        af[2] = (short)f2bf(a0.z); af[3] = (short)f2bf(a0.w);
        af[4] = (short)f2bf(a1.x); af[5] = (short)f2bf(a1.y);
        af[6] = (short)f2bf(a1.z); af[7] = (short)f2bf(a1.w);
        acc0 = __builtin_amdgcn_mfma_f32_16x16x32_bf16(af, bfrag[ks][0], acc0, 0, 0, 0);
        acc1 = __builtin_amdgcn_mfma_f32_16x16x32_bf16(af, bfrag[ks][1], acc1, 0, 0, 0);
    }
    #pragma unroll
    for (int r = 0; r < 4; ++r) {
        const int orow = row0 + kg * 4 + r;
        support[(size_t)orow * OUT_F + mrow]      = f2bf(acc0[r]);
        support[(size_t)orow * OUT_F + mrow + 16] = f2bf(acc1[r]);
    }
}

__global__ __launch_bounds__(256) void gcn_scatter(const int* __restrict__ row,
                                                   const int* __restrict__ col,
                                                   const float* __restrict__ val,
                                                   const unsigned short* __restrict__ sup,
                                                   float* __restrict__ out) {
    const int f = threadIdx.x & 31;
    const int grp = threadIdx.x >> 5;
    long long e = (long long)blockIdx.x * 8 + grp;
    const long long stride = (long long)gridDim.x * 8;
    for (; e < N_EDGES; e += stride) {
        const int r = row[e];
        const int c = col[e];
        const float v = val[e];
        const float s = bf2f(sup[(size_t)c * OUT_F + f]);
        atomicAdd(&out[(size_t)r * OUT_F + f], v * s);
    }
}

extern "C" void kernel_launch(void* const* d_in, const int* in_sizes, int n_in,
                              void* d_out, int out_size, void* d_ws, size_t ws_size,
                              hipStream_t stream) {
    const float* x       = (const float*)d_in[0];
    const int*   adj_row = (const int*)d_in[1];
    const int*   adj_col = (const int*)d_in[2];
    const float* adj_val = (const float*)d_in[3];
    const float* weight  = (const float*)d_in[4];
    const float* bias    = (const float*)d_in[5];
    float* out = (float*)d_out;

    char* ws = (char*)d_ws;
    const size_t SUPPORT_B = (((size_t)N_NODES * OUT_F * 2) + 255) & ~(size_t)255;  // 6.4 MB
    const size_t REC_B     = (((size_t)NB * CAP * 8) + 255) & ~(size_t)255;         // 19.2 MB
    const size_t CUR_B     = (((size_t)NB * 4) + 255) & ~(size_t)255;
    const size_t OCN_B     = 256;
    const size_t OPK_B     = (size_t)N_EDGES * 8;                                   // 12.8 MB
    const size_t OBK_B     = (size_t)N_EDGES * 4;                                   // 6.4 MB
    const size_t NEED = SUPPORT_B + REC_B + CUR_B + OCN_B + OPK_B + OBK_B;

    unsigned short* support = (unsigned short*)(ws);
    long long* rec  = (long long*)(ws + SUPPORT_B);
    int* cur        = (int*)(ws + SUPPORT_B + REC_B);
    int* ovf_cnt    = (int*)(ws + SUPPORT_B + REC_B + CUR_B);
    long long* ovf_pk = (long long*)(ws + SUPPORT_B + REC_B + CUR_B + OCN_B);
    int* ovf_bk     = (int*)(ws + SUPPORT_B + REC_B + CUR_B + OCN_B + OPK_B);

    if (ws_size >= NEED) {
        // K0: cursor init
        gcn_init<<<(NB + 256) / 256, 256, 0, stream>>>(cur, ovf_cnt);
        // K1: fused MFMA gemm || reg-resident bin (hist -> reserve -> scatter)
        gcn_gemm_bin<<<GEMM_BLKS + BBLK, 1024, 0, stream>>>(x, weight, support,
                                                            adj_row, adj_col, adj_val,
                                                            cur, ovf_cnt, rec,
                                                            ovf_pk, ovf_bk);
        // K2: per-bucket counting-sort + pipelined register gather
        gcn_rows<<<NB, 1024, 0, stream>>>(cur, ovf_cnt, rec, ovf_pk, ovf_bk,
                                          support, bias, out);
    } else {
        gcn_gemm_only<<<(MTILES + 7) / 8, 512, 0, stream>>>(x, weight, support);
        gcn_bias_init<<<(N_NODES * OUT_F + 255) / 256, 256, 0, stream>>>(bias, out);
        gcn_scatter<<<8192, 256, 0, stream>>>(adj_row, adj_col, adj_val, support, out);
    }
}